// Round 11
// baseline (2050.738 us; speedup 1.0000x reference)
//
#include <hip/hip_runtime.h>
#include <cstdint>
#include <cstddef>

// Problem constants
#define B_    16
#define N_    4096
#define S_    1024     // NPOINT
#define K_    32       // NSAMPLE
#define CNT_F 524288.0f   // B*S*K
#define EPS_  1e-5f

// Ball-query segmentation (R14-proven): 8 index-range segments per query.
#define SEG_    8
#define SEGLEN_ (N_ / SEG_)   // 512

// Workspace layout (bytes). Total ~188 MB.
#define OFF_NXYZ 0u                    // [B][S][3] f32              196,608
#define OFF_PTST 2293760u              // [B][N][68] f32 (xyz|pts|0) 17,825,792
#define OFF_PRE  20119552u             // [BS][32][64] f16          67,108,864
#define OFF_PRE2 87228416u             // [BS][32][64] f16          67,108,864
#define OFF_PART 154337280u            // (unused since R22)
#define OFF_MM3  171114496u            // [BS][2][128] f32          16,777,216
#define OFF_ACC  187891712u            // [3][256] f32                   3,072
// R19-proven: bq segment scratch lives in the PRE2 region (convB is its
// first writer, strictly after convA — the last segidx reader). Never PRE
// (convA writes pre while reading segidx -> race, R18 crash).
//   segidx [BS][SEG][K] i32 = 16,777,216 ; segcnt [BS][SEG] i32 = 524,288

typedef _Float16 half8 __attribute__((ext_vector_type(8)));

// fma-chain dot4 for conv inner loops (continuous path, fma-safe).
__device__ __forceinline__ float dot4(float acc, float4 f, float4 wt) {
  return fmaf(f.w, wt.w, fmaf(f.z, wt.z, fmaf(f.y, wt.y, fmaf(f.x, wt.x, acc))));
}

// ---------------------------------------------------------------------------
// u64-key DPP max step (R17-proven). Keys are positive-f64 bit patterns
// (sign 0, exponent <= 0x3FB: never NaN/Inf/zero), so v_max_f64 ==
// lexicographic u64 max == the R8-proven comparator (max value, tie -> min
// index). Same rotation network as the proven dpp_argmax_step.
// ---------------------------------------------------------------------------
template <int CTRL, int RM>
__device__ __forceinline__ uint64_t dpp_max64(uint64_t k) {
  int lo = __builtin_amdgcn_update_dpp((int)(uint32_t)k, (int)(uint32_t)k,
                                       CTRL, RM, 0xf, false);
  int hi = __builtin_amdgcn_update_dpp((int)(uint32_t)(k >> 32),
                                       (int)(uint32_t)(k >> 32),
                                       CTRL, RM, 0xf, false);
  uint64_t o = ((uint64_t)(uint32_t)hi << 32) | (uint32_t)lo;
  double m = fmax(__longlong_as_double((long long)k),
                  __longlong_as_double((long long)o));
  return (uint64_t)__double_as_longlong(m);
}

// ---------------------------------------------------------------------------
// FPS — R17/R20-proven form EXACTLY (655 us measured, VGPR 88): u64-key
// tree/DPP, merge keys -> decode far -> sx/sy/sz[far] broadcast reads.
// R21 kill-rule: 256 thr / 4 waves is this structure's optimum (512-thr
// retry with cheap merge still lost: +33 us). Fused transpose on blocks
// >= 16 (R5-proven). Selection arithmetic exact (R1-R17 chain).
// ---------------------------------------------------------------------------
__global__ __launch_bounds__(256) void fps_tr_kernel(
    const float* __restrict__ xyz, const float* __restrict__ pts,
    float* __restrict__ nxyz, float* __restrict__ out0,
    float* __restrict__ ptsT) {
#pragma clang fp contract(off)
  __shared__ __align__(16) char smem[61504];
  int t = threadIdx.x;

  if (blockIdx.x >= B_) {
    // ---------------- transpose role (R0-proven pattern) ----------------
    float* tile = (float*)smem;            // 64*69 floats = 17,664 B
    int blk = blockIdx.x - B_;
    int b = blk >> 6;
    int n0 = (blk & 63) << 6;
    int wave = t >> 6, ln = t & 63;
    int n = n0 + ln;
    for (int cc = wave; cc < 68; cc += 4) {
      float v;
      if (cc < 3)       v = xyz[(size_t)(b * 3 + cc) * N_ + n];
      else if (cc < 67) v = pts[(size_t)(b * 64 + (cc - 3)) * N_ + n];
      else              v = 0.f;
      tile[ln * 69 + cc] = v;
    }
    __syncthreads();
    for (int f = t; f < 64 * 68; f += 256) {
      int r = f / 68, c = f - r * 68;
      ptsT[(size_t)(b * N_ + n0 + r) * 68 + c] = tile[r * 69 + c];
    }
    return;
  }

  // ------------------------- FPS role (R17 verbatim) -------------------------
  float*    sx    = (float*)smem;        // [4096]
  float*    sy    = sx + N_;
  float*    sz    = sy + N_;
  float*    scent = sz + N_;             // [3072]
  uint64_t* skey  = (uint64_t*)(scent + 3 * S_);  // [2][4] (off 61440, 16B ok)

  int b = blockIdx.x;
  const float* xb = xyz + (size_t)b * 3 * N_;
  float xr[16], yr[16], zr[16], dist[16];
  uint32_t Larr[16];
#pragma unroll
  for (int j = 0; j < 16; ++j) {
    int i = j * 256 + t;                      // coalesced: lanes contiguous
    float x = xb[i], y = xb[N_ + i], z = xb[2 * N_ + i];
    xr[j] = x; yr[j] = y; zr[j] = z;
    sx[i] = x; sy[i] = y; sz[i] = z;          // bank = t%32: conflict-free
    dist[j] = 1e10f;
    // j*256 and t occupy disjoint bits -> XOR == 0x7FFFFFFF ^ (j*256+t).
    Larr[j] = 0x7FFFFFFFu ^ (uint32_t)(j * 256 + t);
  }
  __syncthreads();

  int far = 0, par = 0;
  for (int s = 0; s < S_; ++s) {
    float cx = sx[far], cy = sy[far], cz = sz[far];   // uniform broadcast read
    if (t == 0) {
      scent[s * 3]     = cx;
      scent[s * 3 + 1] = cy;
      scent[s * 3 + 2] = cz;
    }
    // Distance update (arithmetic unchanged) + key build.
    uint64_t ku[16];
#pragma unroll
    for (int j = 0; j < 16; ++j) {
      float dx = xr[j] - cx, dy = yr[j] - cy, dz = zr[j] - cz;
      float d = dx * dx + dy * dy + dz * dz;  // left-assoc, no fma
      float nd = fminf(dist[j], d);
      dist[j] = nd;
      ku[j] = ((uint64_t)__float_as_uint(nd) << 31) | Larr[j];
    }
    // Depth-4 max tree over unique keys == keep-left strict-> tree == serial
    // first-index-wins scan. Static indices -> registers.
#pragma unroll
    for (int st = 1; st < 16; st <<= 1) {
#pragma unroll
      for (int j0 = 0; j0 < 16; j0 += (st << 1)) {
        double a = __longlong_as_double((long long)ku[j0]);
        double c2 = __longlong_as_double((long long)ku[j0 + st]);
        ku[j0] = (uint64_t)__double_as_longlong(fmax(a, c2));
      }
    }
    uint64_t k = ku[0];
    // Wave max (VALU-only), winner key in lane 63 of each wave.
    k = dpp_max64<0x121, 0xf>(k);  // row_ror:1
    k = dpp_max64<0x122, 0xf>(k);  // row_ror:2
    k = dpp_max64<0x124, 0xf>(k);  // row_ror:4
    k = dpp_max64<0x128, 0xf>(k);  // row_ror:8
    k = dpp_max64<0x142, 0xa>(k);  // row_bcast15 -> rows 1,3
    k = dpp_max64<0x143, 0xc>(k);  // row_bcast31 -> rows 2,3
    if ((t & 63) == 63) skey[par * 4 + (t >> 6)] = k;
    __syncthreads();
    // Vectorized readback; u64 max over distinct keys (order-independent).
    ulonglong2 p0 = *(const ulonglong2*)&skey[par * 4];
    ulonglong2 p1 = *(const ulonglong2*)&skey[par * 4 + 2];
    uint64_t m = p0.x;
    if (p0.y > m) m = p0.y;
    if (p1.x > m) m = p1.x;
    if (p1.y > m) m = p1.y;
    far = (int)((~(uint32_t)m) & 0xFFFu);   // low 31 bits = 0x7FFFFFFF ^ idx
    par ^= 1;  // double-buffered slots -> one barrier per iteration
  }
  __syncthreads();
  // Coalesced output writes from LDS staging.
  for (int f = t; f < 3 * S_; f += 256)
    nxyz[(size_t)b * 3 * S_ + f] = scent[f];        // [B][S][3]
  for (int s = t; s < S_; s += 256) {               // [B][3][S]
    out0[(size_t)b * 3 * S_ + s]          = scent[s * 3];
    out0[(size_t)b * 3 * S_ + S_ + s]     = scent[s * 3 + 1];
    out0[(size_t)b * 3 * S_ + 2 * S_ + s] = scent[s * 3 + 2];
  }
}

// ---------------------------------------------------------------------------
// Ball query (R14-proven semantics, R19-proven float4 form): 8-way segmented
// scan; per-point fma chain, scan order, and early-exit checks IDENTICAL.
// ---------------------------------------------------------------------------
__global__ __launch_bounds__(64) void bq_seg_kernel(
    const float* __restrict__ xyz, const float* __restrict__ nxyz,
    int* __restrict__ segidx, int* __restrict__ segcnt) {
#pragma clang fp contract(off)
  int q = blockIdx.x * 64 + threadIdx.x;
  int seg = blockIdx.y;
  int b = q >> 10;
  const float* xb = xyz + (size_t)b * 3 * N_;
  float cx = nxyz[(size_t)q * 3];
  float cy = nxyz[(size_t)q * 3 + 1];
  float cz = nxyz[(size_t)q * 3 + 2];
  float A = fmaf(cz, cz, fmaf(cy, cy, cx * cx));
  int* out = segidx + ((size_t)q * SEG_ + seg) * K_;
  int found = 0;
  int i0 = seg * SEGLEN_;
#define BQ_POINT(xx, yy, zz, ii)                                   \
  {                                                                \
    float x = (xx), y = (yy), z = (zz);                            \
    float Bv  = fmaf(z, z, fmaf(y, y, x * x));                     \
    float dot = fmaf(cz, z, fmaf(cy, y, cx * x));                  \
    float d = fmaf(-2.0f, dot, A + Bv);                            \
    if (d <= 0.04f) {                                              \
      out[found] = (ii);                                           \
      ++found;                                                     \
      if (found >= K_) goto done;                                  \
    }                                                              \
  }
  for (int i = i0; i < i0 + SEGLEN_; i += 4) {
    float4 xv = *(const float4*)&xb[i];
    float4 yv = *(const float4*)&xb[N_ + i];
    float4 zv = *(const float4*)&xb[2 * N_ + i];
    BQ_POINT(xv.x, yv.x, zv.x, i)
    BQ_POINT(xv.y, yv.y, zv.y, i + 1)
    BQ_POINT(xv.z, yv.z, zv.z, i + 2)
    BQ_POINT(xv.w, yv.w, zv.w, i + 3)
  }
done:
  segcnt[q * SEG_ + seg] = found;
#undef BQ_POINT
}

// ---------------------------------------------------------------------------
// Layer 0 conv (tiled, validated) with the bq MERGE FUSED IN (R19-proven)
// and, new in R22, the stats reduction fused via fire-and-forget atomicAdd
// (block never reads the result; kernel boundary gives visibility to convB).
// Removes the red_kernel launch + part round-trip. Reduction order changes
// within f32 rounding only (already atomic-nondeterministic before).
// ---------------------------------------------------------------------------
__global__ __launch_bounds__(128) void convA_kernel(
    const float* __restrict__ ptsT, const float* __restrict__ nxyz,
    const int* __restrict__ segidx, const int* __restrict__ segcnt,
    const float* __restrict__ w0, const float* __restrict__ b0,
    _Float16* __restrict__ pre, float* __restrict__ accum_out) {
  __shared__ __align__(16) float sfeat[32 * 72];
  __shared__ __align__(16) float sw[64 * 76];
  __shared__ float red0[64 * 8], red1[64 * 8];
  __shared__ __align__(16) _Float16 sstage[2048];
  __shared__ int sidx[32];
  __shared__ int scnt[8];
  int g = blockIdx.x;
  int t = threadIdx.x;
  int b = g >> 10;
  if (t < 8) scnt[t] = segcnt[(size_t)g * SEG_ + t];
  for (int f = t; f < 64 * 68; f += 128) {
    int c = f / 68, ci = f - c * 68;
    sw[c * 76 + ci] = (ci < 67) ? w0[c * 67 + ci] : 0.f;
  }
  const float* nx = nxyz + (size_t)g * 3;
  float ctr0 = nx[0], ctr1 = nx[1], ctr2 = nx[2];
  __syncthreads();
  if (t < 32) {
    int c0 = scnt[0], c1 = scnt[1], c2 = scnt[2], c3 = scnt[3];
    int c4 = scnt[4], c5 = scnt[5], c6 = scnt[6], c7 = scnt[7];
    int r = t, sel = -1, off = 0;
#define MSTEP(cs, s)                                  \
    if (sel < 0) {                                    \
      if (r < (cs)) { sel = (s); off = r; }           \
      else r -= (cs);                                 \
    }
    MSTEP(c0, 0) MSTEP(c1, 1) MSTEP(c2, 2) MSTEP(c3, 3)
    MSTEP(c4, 4) MSTEP(c5, 5) MSTEP(c6, 6) MSTEP(c7, 7)
#undef MSTEP
    // First non-empty segment (rank-0 source) for the fill value.
    int f0 = (c0 > 0) ? 0 : (c1 > 0) ? 1 : (c2 > 0) ? 2 : (c3 > 0) ? 3
           : (c4 > 0) ? 4 : (c5 > 0) ? 5 : (c6 > 0) ? 6 : 7;
    int sseg = (sel >= 0) ? sel : f0;
    int soff = (sel >= 0) ? off : 0;
    sidx[t] = segidx[((size_t)g * SEG_ + sseg) * K_ + soff];
  }
  __syncthreads();
  for (int f = t; f < 32 * 17; f += 128) {   // 17 float4 per 68-col row
    int k = f / 17, q = f - k * 17;
    float4 v = *(const float4*)&ptsT[(size_t)(b * N_ + sidx[k]) * 68 + q * 4];
    if (q == 0) { v.x -= ctr0; v.y -= ctr1; v.z -= ctr2; }
    *(float4*)&sfeat[k * 72 + q * 4] = v;
  }
  __syncthreads();
  int kq = t & 7, cq = t >> 3;
  float acc[4][4] = {};
  for (int ci = 0; ci < 68; ci += 4) {
    float4 fv[4], wv[4];
#pragma unroll
    for (int kk = 0; kk < 4; ++kk) fv[kk] = *(const float4*)&sfeat[(kq + 8 * kk) * 72 + ci];
#pragma unroll
    for (int cc = 0; cc < 4; ++cc) wv[cc] = *(const float4*)&sw[(cq + 16 * cc) * 76 + ci];
#pragma unroll
    for (int kk = 0; kk < 4; ++kk)
#pragma unroll
      for (int cc = 0; cc < 4; ++cc)
        acc[kk][cc] = dot4(acc[kk][cc], fv[kk], wv[cc]);
  }
#pragma unroll
  for (int cc = 0; cc < 4; ++cc) {
    int c = cq + 16 * cc;
    float bias = b0[c];
    float s1 = 0.f, s2 = 0.f;
#pragma unroll
    for (int kk = 0; kk < 4; ++kk) {
      float v = acc[kk][cc] + bias;
      sstage[(kq + 8 * kk) * 64 + c] = (_Float16)v;
      s1 += v; s2 += v * v;
    }
    red0[c * 8 + kq] = s1; red1[c * 8 + kq] = s2;
  }
  __syncthreads();
  if (t < 64) {
    float s1 = 0.f, s2 = 0.f;
#pragma unroll
    for (int qn = 0; qn < 8; ++qn) { s1 += red0[t * 8 + qn]; s2 += red1[t * 8 + qn]; }
    atomicAdd(accum_out + t, s1);
    atomicAdd(accum_out + 64 + t, s2);
  }
  uint4* dst = (uint4*)(pre + (size_t)g * 2048);
  const uint4* srcv = (const uint4*)sstage;
  dst[t] = srcv[t];
  dst[t + 128] = srcv[t + 128];
}

// ---------------------------------------------------------------------------
// Layer 1 conv (tiled): BN0+relu on pre -> conv w1 -> pre2 + fused stats
// atomics (R22). R16-proven half8/float4 loads. NOTE: pre2 overwrites the
// bq scratch — safe, convA (last segidx reader) completed before this launch.
// ---------------------------------------------------------------------------
__global__ __launch_bounds__(128) void convB_kernel(
    const _Float16* __restrict__ pre, const float* __restrict__ accum,
    const float* __restrict__ gam, const float* __restrict__ bet,
    const float* __restrict__ w1, const float* __restrict__ b1,
    _Float16* __restrict__ pre2, float* __restrict__ accum_out) {
  __shared__ __align__(16) float sfeat[32 * 72];
  __shared__ __align__(16) float sw[64 * 76];
  __shared__ float red0[64 * 8], red1[64 * 8];
  __shared__ __align__(16) _Float16 sstage[2048];
  __shared__ float ssc[64], ssh[64];
  int g = blockIdx.x;
  int t = threadIdx.x;
  if (t < 64) {
    float mu = accum[t] * (1.f / CNT_F);
    float var = accum[64 + t] * (1.f / CNT_F) - mu * mu;
    float sc = gam[t] / sqrtf(var + EPS_);
    ssc[t] = sc; ssh[t] = bet[t] - mu * sc;
  }
  for (int m = t; m < 1024; m += 128) {      // 4096 floats as float4
    int c = m >> 4, ci = (m & 15) * 4;
    *(float4*)&sw[c * 76 + ci] = *(const float4*)&w1[m * 4];
  }
  __syncthreads();
  {
    const half8* src8 = (const half8*)(pre + (size_t)g * 2048);
    int r = t >> 2, c0 = (t & 3) * 16;       // thread owns row r, cols c0..c0+15
    half8 h0 = src8[t * 2], h1 = src8[t * 2 + 1];
#pragma unroll
    for (int e = 0; e < 8; ++e) {
      float v = (float)h0[e] * ssc[c0 + e] + ssh[c0 + e];
      sfeat[r * 72 + c0 + e] = fmaxf(v, 0.f);
    }
#pragma unroll
    for (int e = 0; e < 8; ++e) {
      float v = (float)h1[e] * ssc[c0 + 8 + e] + ssh[c0 + 8 + e];
      sfeat[r * 72 + c0 + 8 + e] = fmaxf(v, 0.f);
    }
  }
  __syncthreads();
  int kq = t & 7, cq = t >> 3;
  float acc[4][4] = {};
  for (int ci = 0; ci < 64; ci += 4) {
    float4 fv[4], wv[4];
#pragma unroll
    for (int kk = 0; kk < 4; ++kk) fv[kk] = *(const float4*)&sfeat[(kq + 8 * kk) * 72 + ci];
#pragma unroll
    for (int cc = 0; cc < 4; ++cc) wv[cc] = *(const float4*)&sw[(cq + 16 * cc) * 76 + ci];
#pragma unroll
    for (int kk = 0; kk < 4; ++kk)
#pragma unroll
      for (int cc = 0; cc < 4; ++cc)
        acc[kk][cc] = dot4(acc[kk][cc], fv[kk], wv[cc]);
  }
#pragma unroll
  for (int cc = 0; cc < 4; ++cc) {
    int c = cq + 16 * cc;
    float bias = b1[c];
    float s1 = 0.f, s2 = 0.f;
#pragma unroll
    for (int kk = 0; kk < 4; ++kk) {
      float v = acc[kk][cc] + bias;
      sstage[(kq + 8 * kk) * 64 + c] = (_Float16)v;
      s1 += v; s2 += v * v;
    }
    red0[c * 8 + kq] = s1; red1[c * 8 + kq] = s2;
  }
  __syncthreads();
  if (t < 64) {
    float s1 = 0.f, s2 = 0.f;
#pragma unroll
    for (int qn = 0; qn < 8; ++qn) { s1 += red0[t * 8 + qn]; s2 += red1[t * 8 + qn]; }
    atomicAdd(accum_out + t, s1);
    atomicAdd(accum_out + 64 + t, s2);
  }
  uint4* dst = (uint4*)(pre2 + (size_t)g * 2048);
  const uint4* srcv = (const uint4*)sstage;
  dst[t] = srcv[t];
  dst[t + 128] = srcv[t + 128];
}

// ---------------------------------------------------------------------------
// Layer 2 conv (tiled): BN1+relu on pre2 -> conv w2 (128 out) -> fused stats
// atomics (R22) + per-group pre-BN max/min over k (relu∘BN monotone).
// ---------------------------------------------------------------------------
__global__ __launch_bounds__(256) void convC_kernel(
    const _Float16* __restrict__ pre2, const float* __restrict__ accum,
    const float* __restrict__ gam, const float* __restrict__ bet,
    const float* __restrict__ w2, const float* __restrict__ b2,
    float* __restrict__ mm, float* __restrict__ accum_out) {
  __shared__ __align__(16) float sfeat[32 * 72];
  __shared__ __align__(16) float sw[128 * 76];
  __shared__ float red0[128 * 8], red1[128 * 8];
  __shared__ float rmax[128 * 8], rmin[128 * 8];
  __shared__ float ssc[64], ssh[64];
  int g = blockIdx.x;
  int t = threadIdx.x;
  if (t < 64) {
    float mu = accum[t] * (1.f / CNT_F);
    float var = accum[64 + t] * (1.f / CNT_F) - mu * mu;
    float sc = gam[t] / sqrtf(var + EPS_);
    ssc[t] = sc; ssh[t] = bet[t] - mu * sc;
  }
  for (int m = t; m < 2048; m += 256) {      // 8192 floats as float4
    int c = m >> 4, ci = (m & 15) * 4;
    *(float4*)&sw[c * 76 + ci] = *(const float4*)&w2[m * 4];
  }
  __syncthreads();
  {
    const half8* src8 = (const half8*)(pre2 + (size_t)g * 2048);
    int r = t >> 3, c0 = (t & 7) * 8;        // thread owns row r, cols c0..c0+7
    half8 h0 = src8[t];
#pragma unroll
    for (int e = 0; e < 8; ++e) {
      float v = (float)h0[e] * ssc[c0 + e] + ssh[c0 + e];
      sfeat[r * 72 + c0 + e] = fmaxf(v, 0.f);
    }
  }
  __syncthreads();
  int kq = t & 7, cq = t >> 3;  // cq 0..31
  float acc[4][4] = {};
  for (int ci = 0; ci < 64; ci += 4) {
    float4 fv[4], wv[4];
#pragma unroll
    for (int kk = 0; kk < 4; ++kk) fv[kk] = *(const float4*)&sfeat[(kq + 8 * kk) * 72 + ci];
#pragma unroll
    for (int cc = 0; cc < 4; ++cc) wv[cc] = *(const float4*)&sw[(cq + 32 * cc) * 76 + ci];
#pragma unroll
    for (int kk = 0; kk < 4; ++kk)
#pragma unroll
      for (int cc = 0; cc < 4; ++cc)
        acc[kk][cc] = dot4(acc[kk][cc], fv[kk], wv[cc]);
  }
#pragma unroll
  for (int cc = 0; cc < 4; ++cc) {
    int c = cq + 32 * cc;
    float bias = b2[c];
    float s1 = 0.f, s2 = 0.f, mx = -3.4e38f, mn = 3.4e38f;
#pragma unroll
    for (int kk = 0; kk < 4; ++kk) {
      float v = acc[kk][cc] + bias;
      s1 += v; s2 += v * v;
      mx = fmaxf(mx, v); mn = fminf(mn, v);
    }
    red0[c * 8 + kq] = s1; red1[c * 8 + kq] = s2;
    rmax[c * 8 + kq] = mx; rmin[c * 8 + kq] = mn;
  }
  __syncthreads();
  if (t < 128) {
    float s1 = 0.f, s2 = 0.f, mx = -3.4e38f, mn = 3.4e38f;
#pragma unroll
    for (int qn = 0; qn < 8; ++qn) {
      s1 += red0[t * 8 + qn]; s2 += red1[t * 8 + qn];
      mx = fmaxf(mx, rmax[t * 8 + qn]); mn = fminf(mn, rmin[t * 8 + qn]);
    }
    atomicAdd(accum_out + t, s1);
    atomicAdd(accum_out + 128 + t, s2);
    mm[(size_t)g * 256 + t] = mx;
    mm[(size_t)g * 256 + 128 + t] = mn;
  }
}

// ---------------------------------------------------------------------------
// Final (coalesced, R8-proven): block = (b, 64-s tile); read mm rows, LDS
// transpose, write out[B,128,S] coalesced in s.
// ---------------------------------------------------------------------------
__global__ __launch_bounds__(256) void fin_kernel(
    const float* __restrict__ mm, const float* __restrict__ accum,
    const float* __restrict__ gam, const float* __restrict__ bet,
    float* __restrict__ out1) {
  __shared__ float tile[128 * 65];
  __shared__ float ssc[128], ssh[128];
  int blk = blockIdx.x;
  int b = blk >> 4;
  int s0 = (blk & 15) << 6;
  int t = threadIdx.x;
  if (t < 128) {
    float mu = accum[t] * (1.f / CNT_F);
    float var = accum[128 + t] * (1.f / CNT_F) - mu * mu;
    float sc = gam[t] / sqrtf(var + EPS_);
    ssc[t] = sc; ssh[t] = bet[t] - mu * sc;
  }
  __syncthreads();
  for (int f = t; f < 64 * 128; f += 256) {
    int sl = f >> 7, c = f & 127;
    const float* row = mm + (size_t)(b * S_ + s0 + sl) * 256;
    float sc = ssc[c];
    float v = (sc >= 0.f) ? row[c] : row[128 + c];
    tile[c * 65 + sl] = fmaxf(v * sc + ssh[c], 0.f);
  }
  __syncthreads();
  for (int f = t; f < 128 * 64; f += 256) {
    int c = f >> 6, sl = f & 63;
    out1[(size_t)b * 131072 + c * 1024 + s0 + sl] = tile[c * 65 + sl];
  }
}

// ---------------------------------------------------------------------------
extern "C" void kernel_launch(void* const* d_in, const int* in_sizes, int n_in,
                              void* d_out, int out_size, void* d_ws, size_t ws_size,
                              hipStream_t stream) {
  const float* xyz = (const float*)d_in[0];
  const float* pts = (const float*)d_in[1];
  const float* w0  = (const float*)d_in[2];
  const float* b0  = (const float*)d_in[3];
  const float* g0  = (const float*)d_in[4];
  const float* bt0 = (const float*)d_in[5];
  const float* w1  = (const float*)d_in[6];
  const float* b1  = (const float*)d_in[7];
  const float* g1  = (const float*)d_in[8];
  const float* bt1 = (const float*)d_in[9];
  const float* w2  = (const float*)d_in[10];
  const float* b2  = (const float*)d_in[11];
  const float* g2  = (const float*)d_in[12];
  const float* bt2 = (const float*)d_in[13];
  float* out = (float*)d_out;

  char* ws = (char*)d_ws;
  float*    nxyz  = (float*)(ws + OFF_NXYZ);
  float*    ptsT  = (float*)(ws + OFF_PTST);
  _Float16* pre   = (_Float16*)(ws + OFF_PRE);
  _Float16* pre2  = (_Float16*)(ws + OFF_PRE2);
  float*    mm    = (float*)(ws + OFF_MM3);
  float*    accum = (float*)(ws + OFF_ACC);
  // R19-proven: bq scratch aliases PRE2 (first written by convB, strictly
  // after convA — the last segidx reader). Never PRE (R18 crash).
  int*      segidx = (int*)(ws + OFF_PRE2);
  int*      segcnt = (int*)(ws + OFF_PRE2 + 16777216u);

  (void)hipMemsetAsync(accum, 0, 3 * 256 * sizeof(float), stream);

  // Fused: blocks 0..15 = FPS (16 CUs busy), blocks 16..1039 = transpose
  // riding on the otherwise-idle 240 CUs.
  fps_tr_kernel<<<B_ + B_ * (N_ / 64), 256, 0, stream>>>(xyz, pts, nxyz, out,
                                                         ptsT);
  bq_seg_kernel<<<dim3((B_ * S_) / 64, SEG_), 64, 0, stream>>>(xyz, nxyz,
                                                               segidx, segcnt);

  // R22: stats reductions fused into the convs (fire-and-forget atomics);
  // red_kernel launches removed. Kernel boundaries provide visibility.
  convA_kernel<<<B_ * S_, 128, 0, stream>>>(ptsT, nxyz, segidx, segcnt, w0, b0,
                                            pre, accum);
  convB_kernel<<<B_ * S_, 128, 0, stream>>>(pre, accum, g0, bt0, w1, b1, pre2,
                                            accum + 256);
  convC_kernel<<<B_ * S_, 256, 0, stream>>>(pre2, accum + 256, g1, bt1, w2, b2,
                                            mm, accum + 512);
  fin_kernel<<<B_ * (S_ / 64), 256, 0, stream>>>(mm, accum + 512, g2, bt2,
                                                 out + B_ * 3 * S_);
}

// Round 12
// 1302.194 us; speedup vs baseline: 1.5748x; 1.5748x over previous
//
#include <hip/hip_runtime.h>
#include <cstdint>
#include <cstddef>

// Problem constants
#define B_    16
#define N_    4096
#define S_    1024     // NPOINT
#define K_    32       // NSAMPLE
#define CNT_F 524288.0f   // B*S*K
#define EPS_  1e-5f

// Ball-query segmentation (R14-proven): 8 index-range segments per query.
#define SEG_    8
#define SEGLEN_ (N_ / SEG_)   // 512

// Workspace layout (bytes). Total ~188 MB.
#define OFF_NXYZ 0u                    // [B][S][3] f32              196,608
#define OFF_PTST 2293760u              // [B][N][68] f32 (xyz|pts|0) 17,825,792
#define OFF_PRE  20119552u             // [BS][32][64] f16          67,108,864
#define OFF_PRE2 87228416u             // [BS][32][64] f16          67,108,864
#define OFF_PART 154337280u            // [BS][256] f32             16,777,216
#define OFF_MM3  171114496u            // [BS][2][128] f32          16,777,216
#define OFF_ACC  187891712u            // [3][256] f32                   3,072
// R19-proven: bq segment scratch lives in the PRE2 region (convB is its
// first writer, strictly after convA — the last segidx reader). Never PRE
// (convA writes pre while reading segidx -> race, R18 crash).
// R22 LESSON: do NOT replace part+red_kernel with per-block atomics — 16384
// blocks x 128-256 atomicAdds to the same words serialize at L2 (+750 us).
//   segidx [BS][SEG][K] i32 = 16,777,216 ; segcnt [BS][SEG] i32 = 524,288

typedef _Float16 half8 __attribute__((ext_vector_type(8)));

// fma-chain dot4 for conv inner loops (continuous path, fma-safe).
__device__ __forceinline__ float dot4(float acc, float4 f, float4 wt) {
  return fmaf(f.w, wt.w, fmaf(f.z, wt.z, fmaf(f.y, wt.y, fmaf(f.x, wt.x, acc))));
}

// ---------------------------------------------------------------------------
// u64-key DPP max step (R17-proven). Keys are positive-f64 bit patterns
// (sign 0, exponent <= 0x3FB: never NaN/Inf/zero), so v_max_f64 ==
// lexicographic u64 max == the R8-proven comparator (max value, tie -> min
// index). Same rotation network as the proven dpp_argmax_step.
// ---------------------------------------------------------------------------
template <int CTRL, int RM>
__device__ __forceinline__ uint64_t dpp_max64(uint64_t k) {
  int lo = __builtin_amdgcn_update_dpp((int)(uint32_t)k, (int)(uint32_t)k,
                                       CTRL, RM, 0xf, false);
  int hi = __builtin_amdgcn_update_dpp((int)(uint32_t)(k >> 32),
                                       (int)(uint32_t)(k >> 32),
                                       CTRL, RM, 0xf, false);
  uint64_t o = ((uint64_t)(uint32_t)hi << 32) | (uint32_t)lo;
  double m = fmax(__longlong_as_double((long long)k),
                  __longlong_as_double((long long)o));
  return (uint64_t)__double_as_longlong(m);
}

// ---------------------------------------------------------------------------
// FPS — R17/R20-proven form (653-656 us measured, VGPR 88): u64-key
// tree/DPP, merge keys -> decode far -> sx/sy/sz[far] broadcast reads.
// 256 thr / 4 waves is this structure's optimum (R13/R21 bracketing).
// Fused transpose on blocks >= 16 (R5-proven). Selection exact (R1-R17).
// ---------------------------------------------------------------------------
__global__ __launch_bounds__(256) void fps_tr_kernel(
    const float* __restrict__ xyz, const float* __restrict__ pts,
    float* __restrict__ nxyz, float* __restrict__ out0,
    float* __restrict__ ptsT) {
#pragma clang fp contract(off)
  __shared__ __align__(16) char smem[61504];
  int t = threadIdx.x;

  if (blockIdx.x >= B_) {
    // ---------------- transpose role (R0-proven pattern) ----------------
    float* tile = (float*)smem;            // 64*69 floats = 17,664 B
    int blk = blockIdx.x - B_;
    int b = blk >> 6;
    int n0 = (blk & 63) << 6;
    int wave = t >> 6, ln = t & 63;
    int n = n0 + ln;
    for (int cc = wave; cc < 68; cc += 4) {
      float v;
      if (cc < 3)       v = xyz[(size_t)(b * 3 + cc) * N_ + n];
      else if (cc < 67) v = pts[(size_t)(b * 64 + (cc - 3)) * N_ + n];
      else              v = 0.f;
      tile[ln * 69 + cc] = v;
    }
    __syncthreads();
    for (int f = t; f < 64 * 68; f += 256) {
      int r = f / 68, c = f - r * 68;
      ptsT[(size_t)(b * N_ + n0 + r) * 68 + c] = tile[r * 69 + c];
    }
    return;
  }

  // ------------------------- FPS role (R17 verbatim) -------------------------
  float*    sx    = (float*)smem;        // [4096]
  float*    sy    = sx + N_;
  float*    sz    = sy + N_;
  float*    scent = sz + N_;             // [3072]
  uint64_t* skey  = (uint64_t*)(scent + 3 * S_);  // [2][4] (off 61440, 16B ok)

  int b = blockIdx.x;
  const float* xb = xyz + (size_t)b * 3 * N_;
  float xr[16], yr[16], zr[16], dist[16];
  uint32_t Larr[16];
#pragma unroll
  for (int j = 0; j < 16; ++j) {
    int i = j * 256 + t;                      // coalesced: lanes contiguous
    float x = xb[i], y = xb[N_ + i], z = xb[2 * N_ + i];
    xr[j] = x; yr[j] = y; zr[j] = z;
    sx[i] = x; sy[i] = y; sz[i] = z;          // bank = t%32: conflict-free
    dist[j] = 1e10f;
    // j*256 and t occupy disjoint bits -> XOR == 0x7FFFFFFF ^ (j*256+t).
    Larr[j] = 0x7FFFFFFFu ^ (uint32_t)(j * 256 + t);
  }
  __syncthreads();

  int far = 0, par = 0;
  for (int s = 0; s < S_; ++s) {
    float cx = sx[far], cy = sy[far], cz = sz[far];   // uniform broadcast read
    if (t == 0) {
      scent[s * 3]     = cx;
      scent[s * 3 + 1] = cy;
      scent[s * 3 + 2] = cz;
    }
    // Distance update (arithmetic unchanged) + key build.
    uint64_t ku[16];
#pragma unroll
    for (int j = 0; j < 16; ++j) {
      float dx = xr[j] - cx, dy = yr[j] - cy, dz = zr[j] - cz;
      float d = dx * dx + dy * dy + dz * dz;  // left-assoc, no fma
      float nd = fminf(dist[j], d);
      dist[j] = nd;
      ku[j] = ((uint64_t)__float_as_uint(nd) << 31) | Larr[j];
    }
    // Depth-4 max tree over unique keys == keep-left strict-> tree == serial
    // first-index-wins scan. Static indices -> registers.
#pragma unroll
    for (int st = 1; st < 16; st <<= 1) {
#pragma unroll
      for (int j0 = 0; j0 < 16; j0 += (st << 1)) {
        double a = __longlong_as_double((long long)ku[j0]);
        double c2 = __longlong_as_double((long long)ku[j0 + st]);
        ku[j0] = (uint64_t)__double_as_longlong(fmax(a, c2));
      }
    }
    uint64_t k = ku[0];
    // Wave max (VALU-only), winner key in lane 63 of each wave.
    k = dpp_max64<0x121, 0xf>(k);  // row_ror:1
    k = dpp_max64<0x122, 0xf>(k);  // row_ror:2
    k = dpp_max64<0x124, 0xf>(k);  // row_ror:4
    k = dpp_max64<0x128, 0xf>(k);  // row_ror:8
    k = dpp_max64<0x142, 0xa>(k);  // row_bcast15 -> rows 1,3
    k = dpp_max64<0x143, 0xc>(k);  // row_bcast31 -> rows 2,3
    if ((t & 63) == 63) skey[par * 4 + (t >> 6)] = k;
    __syncthreads();
    // Vectorized readback; u64 max over distinct keys (order-independent).
    ulonglong2 p0 = *(const ulonglong2*)&skey[par * 4];
    ulonglong2 p1 = *(const ulonglong2*)&skey[par * 4 + 2];
    uint64_t m = p0.x;
    if (p0.y > m) m = p0.y;
    if (p1.x > m) m = p1.x;
    if (p1.y > m) m = p1.y;
    far = (int)((~(uint32_t)m) & 0xFFFu);   // low 31 bits = 0x7FFFFFFF ^ idx
    par ^= 1;  // double-buffered slots -> one barrier per iteration
  }
  __syncthreads();
  // Coalesced output writes from LDS staging.
  for (int f = t; f < 3 * S_; f += 256)
    nxyz[(size_t)b * 3 * S_ + f] = scent[f];        // [B][S][3]
  for (int s = t; s < S_; s += 256) {               // [B][3][S]
    out0[(size_t)b * 3 * S_ + s]          = scent[s * 3];
    out0[(size_t)b * 3 * S_ + S_ + s]     = scent[s * 3 + 1];
    out0[(size_t)b * 3 * S_ + 2 * S_ + s] = scent[s * 3 + 2];
  }
}

// ---------------------------------------------------------------------------
// Ball query (R14-proven semantics, R19-proven float4 form): 8-way segmented
// scan; per-point fma chain, scan order, and early-exit checks IDENTICAL.
// ---------------------------------------------------------------------------
__global__ __launch_bounds__(64) void bq_seg_kernel(
    const float* __restrict__ xyz, const float* __restrict__ nxyz,
    int* __restrict__ segidx, int* __restrict__ segcnt) {
#pragma clang fp contract(off)
  int q = blockIdx.x * 64 + threadIdx.x;
  int seg = blockIdx.y;
  int b = q >> 10;
  const float* xb = xyz + (size_t)b * 3 * N_;
  float cx = nxyz[(size_t)q * 3];
  float cy = nxyz[(size_t)q * 3 + 1];
  float cz = nxyz[(size_t)q * 3 + 2];
  float A = fmaf(cz, cz, fmaf(cy, cy, cx * cx));
  int* out = segidx + ((size_t)q * SEG_ + seg) * K_;
  int found = 0;
  int i0 = seg * SEGLEN_;
#define BQ_POINT(xx, yy, zz, ii)                                   \
  {                                                                \
    float x = (xx), y = (yy), z = (zz);                            \
    float Bv  = fmaf(z, z, fmaf(y, y, x * x));                     \
    float dot = fmaf(cz, z, fmaf(cy, y, cx * x));                  \
    float d = fmaf(-2.0f, dot, A + Bv);                            \
    if (d <= 0.04f) {                                              \
      out[found] = (ii);                                           \
      ++found;                                                     \
      if (found >= K_) goto done;                                  \
    }                                                              \
  }
  for (int i = i0; i < i0 + SEGLEN_; i += 4) {
    float4 xv = *(const float4*)&xb[i];
    float4 yv = *(const float4*)&xb[N_ + i];
    float4 zv = *(const float4*)&xb[2 * N_ + i];
    BQ_POINT(xv.x, yv.x, zv.x, i)
    BQ_POINT(xv.y, yv.y, zv.y, i + 1)
    BQ_POINT(xv.z, yv.z, zv.z, i + 2)
    BQ_POINT(xv.w, yv.w, zv.w, i + 3)
  }
done:
  segcnt[q * SEG_ + seg] = found;
#undef BQ_POINT
}

// ---------------------------------------------------------------------------
// Layer 0 conv (tiled, validated) with the bq MERGE FUSED IN (R19-proven):
// thread k<32 computes the k-th element of the in-order segment concatenation
// via an unrolled prefix chain (exactly bq_merge's semantics); fill = rank-0
// element (always exists: centroid's own d == 0 exactly). Gather/dot/stats
// unchanged (R16-proven).
// ---------------------------------------------------------------------------
__global__ __launch_bounds__(128) void convA_kernel(
    const float* __restrict__ ptsT, const float* __restrict__ nxyz,
    const int* __restrict__ segidx, const int* __restrict__ segcnt,
    const float* __restrict__ w0, const float* __restrict__ b0,
    _Float16* __restrict__ pre, float* __restrict__ part) {
  __shared__ __align__(16) float sfeat[32 * 72];
  __shared__ __align__(16) float sw[64 * 76];
  __shared__ float red0[64 * 8], red1[64 * 8];
  __shared__ __align__(16) _Float16 sstage[2048];
  __shared__ int sidx[32];
  __shared__ int scnt[8];
  int g = blockIdx.x;
  int t = threadIdx.x;
  int b = g >> 10;
  if (t < 8) scnt[t] = segcnt[(size_t)g * SEG_ + t];
  for (int f = t; f < 64 * 68; f += 128) {
    int c = f / 68, ci = f - c * 68;
    sw[c * 76 + ci] = (ci < 67) ? w0[c * 67 + ci] : 0.f;
  }
  const float* nx = nxyz + (size_t)g * 3;
  float ctr0 = nx[0], ctr1 = nx[1], ctr2 = nx[2];
  __syncthreads();
  if (t < 32) {
    int c0 = scnt[0], c1 = scnt[1], c2 = scnt[2], c3 = scnt[3];
    int c4 = scnt[4], c5 = scnt[5], c6 = scnt[6], c7 = scnt[7];
    int r = t, sel = -1, off = 0;
#define MSTEP(cs, s)                                  \
    if (sel < 0) {                                    \
      if (r < (cs)) { sel = (s); off = r; }           \
      else r -= (cs);                                 \
    }
    MSTEP(c0, 0) MSTEP(c1, 1) MSTEP(c2, 2) MSTEP(c3, 3)
    MSTEP(c4, 4) MSTEP(c5, 5) MSTEP(c6, 6) MSTEP(c7, 7)
#undef MSTEP
    // First non-empty segment (rank-0 source) for the fill value.
    int f0 = (c0 > 0) ? 0 : (c1 > 0) ? 1 : (c2 > 0) ? 2 : (c3 > 0) ? 3
           : (c4 > 0) ? 4 : (c5 > 0) ? 5 : (c6 > 0) ? 6 : 7;
    int sseg = (sel >= 0) ? sel : f0;
    int soff = (sel >= 0) ? off : 0;
    sidx[t] = segidx[((size_t)g * SEG_ + sseg) * K_ + soff];
  }
  __syncthreads();
  for (int f = t; f < 32 * 17; f += 128) {   // 17 float4 per 68-col row
    int k = f / 17, q = f - k * 17;
    float4 v = *(const float4*)&ptsT[(size_t)(b * N_ + sidx[k]) * 68 + q * 4];
    if (q == 0) { v.x -= ctr0; v.y -= ctr1; v.z -= ctr2; }
    *(float4*)&sfeat[k * 72 + q * 4] = v;
  }
  __syncthreads();
  int kq = t & 7, cq = t >> 3;
  float acc[4][4] = {};
  for (int ci = 0; ci < 68; ci += 4) {
    float4 fv[4], wv[4];
#pragma unroll
    for (int kk = 0; kk < 4; ++kk) fv[kk] = *(const float4*)&sfeat[(kq + 8 * kk) * 72 + ci];
#pragma unroll
    for (int cc = 0; cc < 4; ++cc) wv[cc] = *(const float4*)&sw[(cq + 16 * cc) * 76 + ci];
#pragma unroll
    for (int kk = 0; kk < 4; ++kk)
#pragma unroll
      for (int cc = 0; cc < 4; ++cc)
        acc[kk][cc] = dot4(acc[kk][cc], fv[kk], wv[cc]);
  }
#pragma unroll
  for (int cc = 0; cc < 4; ++cc) {
    int c = cq + 16 * cc;
    float bias = b0[c];
    float s1 = 0.f, s2 = 0.f;
#pragma unroll
    for (int kk = 0; kk < 4; ++kk) {
      float v = acc[kk][cc] + bias;
      sstage[(kq + 8 * kk) * 64 + c] = (_Float16)v;
      s1 += v; s2 += v * v;
    }
    red0[c * 8 + kq] = s1; red1[c * 8 + kq] = s2;
  }
  __syncthreads();
  if (t < 64) {
    float s1 = 0.f, s2 = 0.f;
#pragma unroll
    for (int qn = 0; qn < 8; ++qn) { s1 += red0[t * 8 + qn]; s2 += red1[t * 8 + qn]; }
    part[(size_t)g * 256 + t] = s1;
    part[(size_t)g * 256 + 64 + t] = s2;
  }
  uint4* dst = (uint4*)(pre + (size_t)g * 2048);
  const uint4* srcv = (const uint4*)sstage;
  dst[t] = srcv[t];
  dst[t + 128] = srcv[t + 128];
}

// ---------------------------------------------------------------------------
// Stats reduce (coalesced, R8-proven): thread t owns channel t; block sums 64
// consecutive rows; one atomicAdd per (block, channel). accum pre-zeroed.
// R22 lesson: this two-level scheme (64-row in-register sum, then ONE atomic
// per block-channel) is required — direct per-conv-block atomics serialize.
// ---------------------------------------------------------------------------
__global__ __launch_bounds__(256) void red_kernel(
    const float* __restrict__ part, float* __restrict__ accum) {
  int t = threadIdx.x;
  size_t base = (size_t)blockIdx.x * 64 * 256 + t;
  float a = 0.f;
#pragma unroll 8
  for (int r = 0; r < 64; ++r) a += part[base + (size_t)r * 256];
  atomicAdd(accum + t, a);
}

// ---------------------------------------------------------------------------
// Layer 1 conv (tiled): BN0+relu on pre -> conv w1 -> pre2 + stats partials.
// R16-proven: half8 activation reads; float4 weight loads. Per-element
// arithmetic unchanged. NOTE: pre2 overwrites the bq scratch — safe, convA
// (last segidx reader) completed before this launch.
// ---------------------------------------------------------------------------
__global__ __launch_bounds__(128) void convB_kernel(
    const _Float16* __restrict__ pre, const float* __restrict__ accum,
    const float* __restrict__ gam, const float* __restrict__ bet,
    const float* __restrict__ w1, const float* __restrict__ b1,
    _Float16* __restrict__ pre2, float* __restrict__ part) {
  __shared__ __align__(16) float sfeat[32 * 72];
  __shared__ __align__(16) float sw[64 * 76];
  __shared__ float red0[64 * 8], red1[64 * 8];
  __shared__ __align__(16) _Float16 sstage[2048];
  __shared__ float ssc[64], ssh[64];
  int g = blockIdx.x;
  int t = threadIdx.x;
  if (t < 64) {
    float mu = accum[t] * (1.f / CNT_F);
    float var = accum[64 + t] * (1.f / CNT_F) - mu * mu;
    float sc = gam[t] / sqrtf(var + EPS_);
    ssc[t] = sc; ssh[t] = bet[t] - mu * sc;
  }
  for (int m = t; m < 1024; m += 128) {      // 4096 floats as float4
    int c = m >> 4, ci = (m & 15) * 4;
    *(float4*)&sw[c * 76 + ci] = *(const float4*)&w1[m * 4];
  }
  __syncthreads();
  {
    const half8* src8 = (const half8*)(pre + (size_t)g * 2048);
    int r = t >> 2, c0 = (t & 3) * 16;       // thread owns row r, cols c0..c0+15
    half8 h0 = src8[t * 2], h1 = src8[t * 2 + 1];
#pragma unroll
    for (int e = 0; e < 8; ++e) {
      float v = (float)h0[e] * ssc[c0 + e] + ssh[c0 + e];
      sfeat[r * 72 + c0 + e] = fmaxf(v, 0.f);
    }
#pragma unroll
    for (int e = 0; e < 8; ++e) {
      float v = (float)h1[e] * ssc[c0 + 8 + e] + ssh[c0 + 8 + e];
      sfeat[r * 72 + c0 + 8 + e] = fmaxf(v, 0.f);
    }
  }
  __syncthreads();
  int kq = t & 7, cq = t >> 3;
  float acc[4][4] = {};
  for (int ci = 0; ci < 64; ci += 4) {
    float4 fv[4], wv[4];
#pragma unroll
    for (int kk = 0; kk < 4; ++kk) fv[kk] = *(const float4*)&sfeat[(kq + 8 * kk) * 72 + ci];
#pragma unroll
    for (int cc = 0; cc < 4; ++cc) wv[cc] = *(const float4*)&sw[(cq + 16 * cc) * 76 + ci];
#pragma unroll
    for (int kk = 0; kk < 4; ++kk)
#pragma unroll
      for (int cc = 0; cc < 4; ++cc)
        acc[kk][cc] = dot4(acc[kk][cc], fv[kk], wv[cc]);
  }
#pragma unroll
  for (int cc = 0; cc < 4; ++cc) {
    int c = cq + 16 * cc;
    float bias = b1[c];
    float s1 = 0.f, s2 = 0.f;
#pragma unroll
    for (int kk = 0; kk < 4; ++kk) {
      float v = acc[kk][cc] + bias;
      sstage[(kq + 8 * kk) * 64 + c] = (_Float16)v;
      s1 += v; s2 += v * v;
    }
    red0[c * 8 + kq] = s1; red1[c * 8 + kq] = s2;
  }
  __syncthreads();
  if (t < 64) {
    float s1 = 0.f, s2 = 0.f;
#pragma unroll
    for (int qn = 0; qn < 8; ++qn) { s1 += red0[t * 8 + qn]; s2 += red1[t * 8 + qn]; }
    part[(size_t)g * 256 + t] = s1;
    part[(size_t)g * 256 + 64 + t] = s2;
  }
  uint4* dst = (uint4*)(pre2 + (size_t)g * 2048);
  const uint4* srcv = (const uint4*)sstage;
  dst[t] = srcv[t];
  dst[t + 128] = srcv[t + 128];
}

// ---------------------------------------------------------------------------
// Layer 2 conv (tiled): BN1+relu on pre2 -> conv w2 (128 out) -> stats
// partials + per-group pre-BN max/min over k (relu∘BN monotone).
// R16-proven: half8 activation reads; float4 weight loads.
// ---------------------------------------------------------------------------
__global__ __launch_bounds__(256) void convC_kernel(
    const _Float16* __restrict__ pre2, const float* __restrict__ accum,
    const float* __restrict__ gam, const float* __restrict__ bet,
    const float* __restrict__ w2, const float* __restrict__ b2,
    float* __restrict__ mm, float* __restrict__ part) {
  __shared__ __align__(16) float sfeat[32 * 72];
  __shared__ __align__(16) float sw[128 * 76];
  __shared__ float red0[128 * 8], red1[128 * 8];
  __shared__ float rmax[128 * 8], rmin[128 * 8];
  __shared__ float ssc[64], ssh[64];
  int g = blockIdx.x;
  int t = threadIdx.x;
  if (t < 64) {
    float mu = accum[t] * (1.f / CNT_F);
    float var = accum[64 + t] * (1.f / CNT_F) - mu * mu;
    float sc = gam[t] / sqrtf(var + EPS_);
    ssc[t] = sc; ssh[t] = bet[t] - mu * sc;
  }
  for (int m = t; m < 2048; m += 256) {      // 8192 floats as float4
    int c = m >> 4, ci = (m & 15) * 4;
    *(float4*)&sw[c * 76 + ci] = *(const float4*)&w2[m * 4];
  }
  __syncthreads();
  {
    const half8* src8 = (const half8*)(pre2 + (size_t)g * 2048);
    int r = t >> 3, c0 = (t & 7) * 8;        // thread owns row r, cols c0..c0+7
    half8 h0 = src8[t];
#pragma unroll
    for (int e = 0; e < 8; ++e) {
      float v = (float)h0[e] * ssc[c0 + e] + ssh[c0 + e];
      sfeat[r * 72 + c0 + e] = fmaxf(v, 0.f);
    }
  }
  __syncthreads();
  int kq = t & 7, cq = t >> 3;  // cq 0..31
  float acc[4][4] = {};
  for (int ci = 0; ci < 64; ci += 4) {
    float4 fv[4], wv[4];
#pragma unroll
    for (int kk = 0; kk < 4; ++kk) fv[kk] = *(const float4*)&sfeat[(kq + 8 * kk) * 72 + ci];
#pragma unroll
    for (int cc = 0; cc < 4; ++cc) wv[cc] = *(const float4*)&sw[(cq + 32 * cc) * 76 + ci];
#pragma unroll
    for (int kk = 0; kk < 4; ++kk)
#pragma unroll
      for (int cc = 0; cc < 4; ++cc)
        acc[kk][cc] = dot4(acc[kk][cc], fv[kk], wv[cc]);
  }
#pragma unroll
  for (int cc = 0; cc < 4; ++cc) {
    int c = cq + 32 * cc;
    float bias = b2[c];
    float s1 = 0.f, s2 = 0.f, mx = -3.4e38f, mn = 3.4e38f;
#pragma unroll
    for (int kk = 0; kk < 4; ++kk) {
      float v = acc[kk][cc] + bias;
      s1 += v; s2 += v * v;
      mx = fmaxf(mx, v); mn = fminf(mn, v);
    }
    red0[c * 8 + kq] = s1; red1[c * 8 + kq] = s2;
    rmax[c * 8 + kq] = mx; rmin[c * 8 + kq] = mn;
  }
  __syncthreads();
  if (t < 128) {
    float s1 = 0.f, s2 = 0.f, mx = -3.4e38f, mn = 3.4e38f;
#pragma unroll
    for (int qn = 0; qn < 8; ++qn) {
      s1 += red0[t * 8 + qn]; s2 += red1[t * 8 + qn];
      mx = fmaxf(mx, rmax[t * 8 + qn]); mn = fminf(mn, rmin[t * 8 + qn]);
    }
    part[(size_t)g * 256 + t] = s1;
    part[(size_t)g * 256 + 128 + t] = s2;
    mm[(size_t)g * 256 + t] = mx;
    mm[(size_t)g * 256 + 128 + t] = mn;
  }
}

// ---------------------------------------------------------------------------
// Final (coalesced, R8-proven): block = (b, 64-s tile); read mm rows, LDS
// transpose, write out[B,128,S] coalesced in s.
// ---------------------------------------------------------------------------
__global__ __launch_bounds__(256) void fin_kernel(
    const float* __restrict__ mm, const float* __restrict__ accum,
    const float* __restrict__ gam, const float* __restrict__ bet,
    float* __restrict__ out1) {
  __shared__ float tile[128 * 65];
  __shared__ float ssc[128], ssh[128];
  int blk = blockIdx.x;
  int b = blk >> 4;
  int s0 = (blk & 15) << 6;
  int t = threadIdx.x;
  if (t < 128) {
    float mu = accum[t] * (1.f / CNT_F);
    float var = accum[128 + t] * (1.f / CNT_F) - mu * mu;
    float sc = gam[t] / sqrtf(var + EPS_);
    ssc[t] = sc; ssh[t] = bet[t] - mu * sc;
  }
  __syncthreads();
  for (int f = t; f < 64 * 128; f += 256) {
    int sl = f >> 7, c = f & 127;
    const float* row = mm + (size_t)(b * S_ + s0 + sl) * 256;
    float sc = ssc[c];
    float v = (sc >= 0.f) ? row[c] : row[128 + c];
    tile[c * 65 + sl] = fmaxf(v * sc + ssh[c], 0.f);
  }
  __syncthreads();
  for (int f = t; f < 128 * 64; f += 256) {
    int c = f >> 6, sl = f & 63;
    out1[(size_t)b * 131072 + c * 1024 + s0 + sl] = tile[c * 65 + sl];
  }
}

// ---------------------------------------------------------------------------
extern "C" void kernel_launch(void* const* d_in, const int* in_sizes, int n_in,
                              void* d_out, int out_size, void* d_ws, size_t ws_size,
                              hipStream_t stream) {
  const float* xyz = (const float*)d_in[0];
  const float* pts = (const float*)d_in[1];
  const float* w0  = (const float*)d_in[2];
  const float* b0  = (const float*)d_in[3];
  const float* g0  = (const float*)d_in[4];
  const float* bt0 = (const float*)d_in[5];
  const float* w1  = (const float*)d_in[6];
  const float* b1  = (const float*)d_in[7];
  const float* g1  = (const float*)d_in[8];
  const float* bt1 = (const float*)d_in[9];
  const float* w2  = (const float*)d_in[10];
  const float* b2  = (const float*)d_in[11];
  const float* g2  = (const float*)d_in[12];
  const float* bt2 = (const float*)d_in[13];
  float* out = (float*)d_out;

  char* ws = (char*)d_ws;
  float*    nxyz  = (float*)(ws + OFF_NXYZ);
  float*    ptsT  = (float*)(ws + OFF_PTST);
  _Float16* pre   = (_Float16*)(ws + OFF_PRE);
  _Float16* pre2  = (_Float16*)(ws + OFF_PRE2);
  float*    part  = (float*)(ws + OFF_PART);
  float*    mm    = (float*)(ws + OFF_MM3);
  float*    accum = (float*)(ws + OFF_ACC);
  // R19-proven: bq scratch aliases PRE2 (first written by convB, strictly
  // after convA — the last segidx reader). Never PRE (R18 crash).
  int*      segidx = (int*)(ws + OFF_PRE2);
  int*      segcnt = (int*)(ws + OFF_PRE2 + 16777216u);

  (void)hipMemsetAsync(accum, 0, 3 * 256 * sizeof(float), stream);

  // Fused: blocks 0..15 = FPS (16 CUs busy), blocks 16..1039 = transpose
  // riding on the otherwise-idle 240 CUs.
  fps_tr_kernel<<<B_ + B_ * (N_ / 64), 256, 0, stream>>>(xyz, pts, nxyz, out,
                                                         ptsT);
  bq_seg_kernel<<<dim3((B_ * S_) / 64, SEG_), 64, 0, stream>>>(xyz, nxyz,
                                                               segidx, segcnt);

  convA_kernel<<<B_ * S_, 128, 0, stream>>>(ptsT, nxyz, segidx, segcnt, w0, b0,
                                            pre, part);
  red_kernel<<<256, 256, 0, stream>>>(part, accum);
  convB_kernel<<<B_ * S_, 128, 0, stream>>>(pre, accum, g0, bt0, w1, b1, pre2, part);
  red_kernel<<<256, 256, 0, stream>>>(part, accum + 256);
  convC_kernel<<<B_ * S_, 256, 0, stream>>>(pre2, accum + 256, g1, bt1, w2, b2, mm, part);
  red_kernel<<<256, 256, 0, stream>>>(part, accum + 512);
  fin_kernel<<<B_ * (S_ / 64), 256, 0, stream>>>(mm, accum + 512, g2, bt2,
                                                 out + B_ * 3 * S_);
}

// Round 13
// 1215.922 us; speedup vs baseline: 1.6866x; 1.0710x over previous
//
#include <hip/hip_runtime.h>
#include <cstdint>
#include <cstddef>

// Problem constants
#define B_    16
#define N_    4096
#define S_    1024     // NPOINT
#define K_    32       // NSAMPLE
#define CNT_F 524288.0f   // B*S*K
#define EPS_  1e-5f

// Ball-query segmentation (R14-proven): 8 index-range segments per query.
#define SEG_    8
#define SEGLEN_ (N_ / SEG_)   // 512

// Workspace layout (bytes). Total ~188 MB.
#define OFF_NXYZ 0u                    // [B][S][3] f32              196,608
#define OFF_PTST 2293760u              // [B][N][68] f32 (xyz|pts|0) 17,825,792
#define OFF_PRE  20119552u             // [BS][32][64] f16          67,108,864
#define OFF_PRE2 87228416u             // [BS][32][64] f16          67,108,864
#define OFF_PART 154337280u            // [BS][256] f32             16,777,216
#define OFF_MM3  171114496u            // [BS][2][128] f32          16,777,216
#define OFF_ACC  187891712u            // [3][256] f32                   3,072
// R19-proven: bq segment scratch lives in the PRE2 region (convB is its
// first writer, strictly after convA — the last segidx reader). Never PRE
// (convA writes pre while reading segidx -> race, R18 crash).
// R22 LESSON: do NOT replace part+red_kernel with per-block atomics — 16384
// blocks x 128-256 atomicAdds to the same words serialize at L2 (+750 us).
//   segidx [BS][SEG][K] i32 = 16,777,216 ; segcnt [BS][SEG] i32 = 524,288

typedef _Float16 half8 __attribute__((ext_vector_type(8)));
typedef float f32x4 __attribute__((ext_vector_type(4)));

// fma-chain dot4 for conv inner loops (continuous path, fma-safe).
__device__ __forceinline__ float dot4(float acc, float4 f, float4 wt) {
  return fmaf(f.w, wt.w, fmaf(f.z, wt.z, fmaf(f.y, wt.y, fmaf(f.x, wt.x, acc))));
}

// ---------------------------------------------------------------------------
// u64-key DPP max step (R17-proven). Keys are positive-f64 bit patterns
// (sign 0, exponent <= 0x3FB: never NaN/Inf/zero), so v_max_f64 ==
// lexicographic u64 max == the R8-proven comparator (max value, tie -> min
// index). Same rotation network as the proven dpp_argmax_step.
// ---------------------------------------------------------------------------
template <int CTRL, int RM>
__device__ __forceinline__ uint64_t dpp_max64(uint64_t k) {
  int lo = __builtin_amdgcn_update_dpp((int)(uint32_t)k, (int)(uint32_t)k,
                                       CTRL, RM, 0xf, false);
  int hi = __builtin_amdgcn_update_dpp((int)(uint32_t)(k >> 32),
                                       (int)(uint32_t)(k >> 32),
                                       CTRL, RM, 0xf, false);
  uint64_t o = ((uint64_t)(uint32_t)hi << 32) | (uint32_t)lo;
  double m = fmax(__longlong_as_double((long long)k),
                  __longlong_as_double((long long)o));
  return (uint64_t)__double_as_longlong(m);
}

// ---------------------------------------------------------------------------
// FPS — R17/R20-proven form (653-656 us measured, VGPR 88): u64-key
// tree/DPP, merge keys -> decode far -> sx/sy/sz[far] broadcast reads.
// 256 thr / 4 waves is this structure's optimum (R13/R21 bracketing).
// Fused transpose on blocks >= 16 (R5-proven). Selection exact (R1-R17).
// ---------------------------------------------------------------------------
__global__ __launch_bounds__(256) void fps_tr_kernel(
    const float* __restrict__ xyz, const float* __restrict__ pts,
    float* __restrict__ nxyz, float* __restrict__ out0,
    float* __restrict__ ptsT) {
#pragma clang fp contract(off)
  __shared__ __align__(16) char smem[61504];
  int t = threadIdx.x;

  if (blockIdx.x >= B_) {
    // ---------------- transpose role (R0-proven pattern) ----------------
    float* tile = (float*)smem;            // 64*69 floats = 17,664 B
    int blk = blockIdx.x - B_;
    int b = blk >> 6;
    int n0 = (blk & 63) << 6;
    int wave = t >> 6, ln = t & 63;
    int n = n0 + ln;
    for (int cc = wave; cc < 68; cc += 4) {
      float v;
      if (cc < 3)       v = xyz[(size_t)(b * 3 + cc) * N_ + n];
      else if (cc < 67) v = pts[(size_t)(b * 64 + (cc - 3)) * N_ + n];
      else              v = 0.f;
      tile[ln * 69 + cc] = v;
    }
    __syncthreads();
    for (int f = t; f < 64 * 68; f += 256) {
      int r = f / 68, c = f - r * 68;
      ptsT[(size_t)(b * N_ + n0 + r) * 68 + c] = tile[r * 69 + c];
    }
    return;
  }

  // ------------------------- FPS role (R17 verbatim) -------------------------
  float*    sx    = (float*)smem;        // [4096]
  float*    sy    = sx + N_;
  float*    sz    = sy + N_;
  float*    scent = sz + N_;             // [3072]
  uint64_t* skey  = (uint64_t*)(scent + 3 * S_);  // [2][4] (off 61440, 16B ok)

  int b = blockIdx.x;
  const float* xb = xyz + (size_t)b * 3 * N_;
  float xr[16], yr[16], zr[16], dist[16];
  uint32_t Larr[16];
#pragma unroll
  for (int j = 0; j < 16; ++j) {
    int i = j * 256 + t;                      // coalesced: lanes contiguous
    float x = xb[i], y = xb[N_ + i], z = xb[2 * N_ + i];
    xr[j] = x; yr[j] = y; zr[j] = z;
    sx[i] = x; sy[i] = y; sz[i] = z;          // bank = t%32: conflict-free
    dist[j] = 1e10f;
    // j*256 and t occupy disjoint bits -> XOR == 0x7FFFFFFF ^ (j*256+t).
    Larr[j] = 0x7FFFFFFFu ^ (uint32_t)(j * 256 + t);
  }
  __syncthreads();

  int far = 0, par = 0;
  for (int s = 0; s < S_; ++s) {
    float cx = sx[far], cy = sy[far], cz = sz[far];   // uniform broadcast read
    if (t == 0) {
      scent[s * 3]     = cx;
      scent[s * 3 + 1] = cy;
      scent[s * 3 + 2] = cz;
    }
    // Distance update (arithmetic unchanged) + key build.
    uint64_t ku[16];
#pragma unroll
    for (int j = 0; j < 16; ++j) {
      float dx = xr[j] - cx, dy = yr[j] - cy, dz = zr[j] - cz;
      float d = dx * dx + dy * dy + dz * dz;  // left-assoc, no fma
      float nd = fminf(dist[j], d);
      dist[j] = nd;
      ku[j] = ((uint64_t)__float_as_uint(nd) << 31) | Larr[j];
    }
    // Depth-4 max tree over unique keys == keep-left strict-> tree == serial
    // first-index-wins scan. Static indices -> registers.
#pragma unroll
    for (int st = 1; st < 16; st <<= 1) {
#pragma unroll
      for (int j0 = 0; j0 < 16; j0 += (st << 1)) {
        double a = __longlong_as_double((long long)ku[j0]);
        double c2 = __longlong_as_double((long long)ku[j0 + st]);
        ku[j0] = (uint64_t)__double_as_longlong(fmax(a, c2));
      }
    }
    uint64_t k = ku[0];
    // Wave max (VALU-only), winner key in lane 63 of each wave.
    k = dpp_max64<0x121, 0xf>(k);  // row_ror:1
    k = dpp_max64<0x122, 0xf>(k);  // row_ror:2
    k = dpp_max64<0x124, 0xf>(k);  // row_ror:4
    k = dpp_max64<0x128, 0xf>(k);  // row_ror:8
    k = dpp_max64<0x142, 0xa>(k);  // row_bcast15 -> rows 1,3
    k = dpp_max64<0x143, 0xc>(k);  // row_bcast31 -> rows 2,3
    if ((t & 63) == 63) skey[par * 4 + (t >> 6)] = k;
    __syncthreads();
    // Vectorized readback; u64 max over distinct keys (order-independent).
    ulonglong2 p0 = *(const ulonglong2*)&skey[par * 4];
    ulonglong2 p1 = *(const ulonglong2*)&skey[par * 4 + 2];
    uint64_t m = p0.x;
    if (p0.y > m) m = p0.y;
    if (p1.x > m) m = p1.x;
    if (p1.y > m) m = p1.y;
    far = (int)((~(uint32_t)m) & 0xFFFu);   // low 31 bits = 0x7FFFFFFF ^ idx
    par ^= 1;  // double-buffered slots -> one barrier per iteration
  }
  __syncthreads();
  // Coalesced output writes from LDS staging.
  for (int f = t; f < 3 * S_; f += 256)
    nxyz[(size_t)b * 3 * S_ + f] = scent[f];        // [B][S][3]
  for (int s = t; s < S_; s += 256) {               // [B][3][S]
    out0[(size_t)b * 3 * S_ + s]          = scent[s * 3];
    out0[(size_t)b * 3 * S_ + S_ + s]     = scent[s * 3 + 1];
    out0[(size_t)b * 3 * S_ + 2 * S_ + s] = scent[s * 3 + 2];
  }
}

// ---------------------------------------------------------------------------
// Ball query (R14-proven semantics, R19-proven float4 form): 8-way segmented
// scan; per-point fma chain, scan order, and early-exit checks IDENTICAL.
// ---------------------------------------------------------------------------
__global__ __launch_bounds__(64) void bq_seg_kernel(
    const float* __restrict__ xyz, const float* __restrict__ nxyz,
    int* __restrict__ segidx, int* __restrict__ segcnt) {
#pragma clang fp contract(off)
  int q = blockIdx.x * 64 + threadIdx.x;
  int seg = blockIdx.y;
  int b = q >> 10;
  const float* xb = xyz + (size_t)b * 3 * N_;
  float cx = nxyz[(size_t)q * 3];
  float cy = nxyz[(size_t)q * 3 + 1];
  float cz = nxyz[(size_t)q * 3 + 2];
  float A = fmaf(cz, cz, fmaf(cy, cy, cx * cx));
  int* out = segidx + ((size_t)q * SEG_ + seg) * K_;
  int found = 0;
  int i0 = seg * SEGLEN_;
#define BQ_POINT(xx, yy, zz, ii)                                   \
  {                                                                \
    float x = (xx), y = (yy), z = (zz);                            \
    float Bv  = fmaf(z, z, fmaf(y, y, x * x));                     \
    float dot = fmaf(cz, z, fmaf(cy, y, cx * x));                  \
    float d = fmaf(-2.0f, dot, A + Bv);                            \
    if (d <= 0.04f) {                                              \
      out[found] = (ii);                                           \
      ++found;                                                     \
      if (found >= K_) goto done;                                  \
    }                                                              \
  }
  for (int i = i0; i < i0 + SEGLEN_; i += 4) {
    float4 xv = *(const float4*)&xb[i];
    float4 yv = *(const float4*)&xb[N_ + i];
    float4 zv = *(const float4*)&xb[2 * N_ + i];
    BQ_POINT(xv.x, yv.x, zv.x, i)
    BQ_POINT(xv.y, yv.y, zv.y, i + 1)
    BQ_POINT(xv.z, yv.z, zv.z, i + 2)
    BQ_POINT(xv.w, yv.w, zv.w, i + 3)
  }
done:
  segcnt[q * SEG_ + seg] = found;
#undef BQ_POINT
}

// ---------------------------------------------------------------------------
// Layer 0 conv (tiled, validated) with the bq MERGE FUSED IN (R19-proven):
// thread k<32 computes the k-th element of the in-order segment concatenation
// via an unrolled prefix chain (exactly bq_merge's semantics); fill = rank-0
// element (always exists: centroid's own d == 0 exactly). Gather/dot/stats
// unchanged (R16-proven).
// ---------------------------------------------------------------------------
__global__ __launch_bounds__(128) void convA_kernel(
    const float* __restrict__ ptsT, const float* __restrict__ nxyz,
    const int* __restrict__ segidx, const int* __restrict__ segcnt,
    const float* __restrict__ w0, const float* __restrict__ b0,
    _Float16* __restrict__ pre, float* __restrict__ part) {
  __shared__ __align__(16) float sfeat[32 * 72];
  __shared__ __align__(16) float sw[64 * 76];
  __shared__ float red0[64 * 8], red1[64 * 8];
  __shared__ __align__(16) _Float16 sstage[2048];
  __shared__ int sidx[32];
  __shared__ int scnt[8];
  int g = blockIdx.x;
  int t = threadIdx.x;
  int b = g >> 10;
  if (t < 8) scnt[t] = segcnt[(size_t)g * SEG_ + t];
  for (int f = t; f < 64 * 68; f += 128) {
    int c = f / 68, ci = f - c * 68;
    sw[c * 76 + ci] = (ci < 67) ? w0[c * 67 + ci] : 0.f;
  }
  const float* nx = nxyz + (size_t)g * 3;
  float ctr0 = nx[0], ctr1 = nx[1], ctr2 = nx[2];
  __syncthreads();
  if (t < 32) {
    int c0 = scnt[0], c1 = scnt[1], c2 = scnt[2], c3 = scnt[3];
    int c4 = scnt[4], c5 = scnt[5], c6 = scnt[6], c7 = scnt[7];
    int r = t, sel = -1, off = 0;
#define MSTEP(cs, s)                                  \
    if (sel < 0) {                                    \
      if (r < (cs)) { sel = (s); off = r; }           \
      else r -= (cs);                                 \
    }
    MSTEP(c0, 0) MSTEP(c1, 1) MSTEP(c2, 2) MSTEP(c3, 3)
    MSTEP(c4, 4) MSTEP(c5, 5) MSTEP(c6, 6) MSTEP(c7, 7)
#undef MSTEP
    // First non-empty segment (rank-0 source) for the fill value.
    int f0 = (c0 > 0) ? 0 : (c1 > 0) ? 1 : (c2 > 0) ? 2 : (c3 > 0) ? 3
           : (c4 > 0) ? 4 : (c5 > 0) ? 5 : (c6 > 0) ? 6 : 7;
    int sseg = (sel >= 0) ? sel : f0;
    int soff = (sel >= 0) ? off : 0;
    sidx[t] = segidx[((size_t)g * SEG_ + sseg) * K_ + soff];
  }
  __syncthreads();
  for (int f = t; f < 32 * 17; f += 128) {   // 17 float4 per 68-col row
    int k = f / 17, q = f - k * 17;
    float4 v = *(const float4*)&ptsT[(size_t)(b * N_ + sidx[k]) * 68 + q * 4];
    if (q == 0) { v.x -= ctr0; v.y -= ctr1; v.z -= ctr2; }
    *(float4*)&sfeat[k * 72 + q * 4] = v;
  }
  __syncthreads();
  int kq = t & 7, cq = t >> 3;
  float acc[4][4] = {};
  for (int ci = 0; ci < 68; ci += 4) {
    float4 fv[4], wv[4];
#pragma unroll
    for (int kk = 0; kk < 4; ++kk) fv[kk] = *(const float4*)&sfeat[(kq + 8 * kk) * 72 + ci];
#pragma unroll
    for (int cc = 0; cc < 4; ++cc) wv[cc] = *(const float4*)&sw[(cq + 16 * cc) * 76 + ci];
#pragma unroll
    for (int kk = 0; kk < 4; ++kk)
#pragma unroll
      for (int cc = 0; cc < 4; ++cc)
        acc[kk][cc] = dot4(acc[kk][cc], fv[kk], wv[cc]);
  }
#pragma unroll
  for (int cc = 0; cc < 4; ++cc) {
    int c = cq + 16 * cc;
    float bias = b0[c];
    float s1 = 0.f, s2 = 0.f;
#pragma unroll
    for (int kk = 0; kk < 4; ++kk) {
      float v = acc[kk][cc] + bias;
      sstage[(kq + 8 * kk) * 64 + c] = (_Float16)v;
      s1 += v; s2 += v * v;
    }
    red0[c * 8 + kq] = s1; red1[c * 8 + kq] = s2;
  }
  __syncthreads();
  if (t < 64) {
    float s1 = 0.f, s2 = 0.f;
#pragma unroll
    for (int qn = 0; qn < 8; ++qn) { s1 += red0[t * 8 + qn]; s2 += red1[t * 8 + qn]; }
    part[(size_t)g * 256 + t] = s1;
    part[(size_t)g * 256 + 64 + t] = s2;
  }
  uint4* dst = (uint4*)(pre + (size_t)g * 2048);
  const uint4* srcv = (const uint4*)sstage;
  dst[t] = srcv[t];
  dst[t + 128] = srcv[t + 128];
}

// ---------------------------------------------------------------------------
// Stats reduce (coalesced, R8-proven): thread t owns channel t; block sums 64
// consecutive rows; one atomicAdd per (block, channel). accum pre-zeroed.
// R22 lesson: this two-level scheme (64-row in-register sum, then ONE atomic
// per block-channel) is required — direct per-conv-block atomics serialize.
// ---------------------------------------------------------------------------
__global__ __launch_bounds__(256) void red_kernel(
    const float* __restrict__ part, float* __restrict__ accum) {
  int t = threadIdx.x;
  size_t base = (size_t)blockIdx.x * 64 * 256 + t;
  float a = 0.f;
#pragma unroll 8
  for (int r = 0; r < 64; ++r) a += part[base + (size_t)r * 256];
  atomicAdd(accum + t, a);
}

// ---------------------------------------------------------------------------
// Layer 1 conv (tiled): BN0+relu on pre -> conv w1 -> pre2 + stats partials.
// R16-proven: half8 activation reads; float4 weight loads. Per-element
// arithmetic unchanged. NOTE: pre2 overwrites the bq scratch — safe, convA
// (last segidx reader) completed before this launch.
// ---------------------------------------------------------------------------
__global__ __launch_bounds__(128) void convB_kernel(
    const _Float16* __restrict__ pre, const float* __restrict__ accum,
    const float* __restrict__ gam, const float* __restrict__ bet,
    const float* __restrict__ w1, const float* __restrict__ b1,
    _Float16* __restrict__ pre2, float* __restrict__ part) {
  __shared__ __align__(16) float sfeat[32 * 72];
  __shared__ __align__(16) float sw[64 * 76];
  __shared__ float red0[64 * 8], red1[64 * 8];
  __shared__ __align__(16) _Float16 sstage[2048];
  __shared__ float ssc[64], ssh[64];
  int g = blockIdx.x;
  int t = threadIdx.x;
  if (t < 64) {
    float mu = accum[t] * (1.f / CNT_F);
    float var = accum[64 + t] * (1.f / CNT_F) - mu * mu;
    float sc = gam[t] / sqrtf(var + EPS_);
    ssc[t] = sc; ssh[t] = bet[t] - mu * sc;
  }
  for (int m = t; m < 1024; m += 128) {      // 4096 floats as float4
    int c = m >> 4, ci = (m & 15) * 4;
    *(float4*)&sw[c * 76 + ci] = *(const float4*)&w1[m * 4];
  }
  __syncthreads();
  {
    const half8* src8 = (const half8*)(pre + (size_t)g * 2048);
    int r = t >> 2, c0 = (t & 3) * 16;       // thread owns row r, cols c0..c0+15
    half8 h0 = src8[t * 2], h1 = src8[t * 2 + 1];
#pragma unroll
    for (int e = 0; e < 8; ++e) {
      float v = (float)h0[e] * ssc[c0 + e] + ssh[c0 + e];
      sfeat[r * 72 + c0 + e] = fmaxf(v, 0.f);
    }
#pragma unroll
    for (int e = 0; e < 8; ++e) {
      float v = (float)h1[e] * ssc[c0 + 8 + e] + ssh[c0 + 8 + e];
      sfeat[r * 72 + c0 + 8 + e] = fmaxf(v, 0.f);
    }
  }
  __syncthreads();
  int kq = t & 7, cq = t >> 3;
  float acc[4][4] = {};
  for (int ci = 0; ci < 64; ci += 4) {
    float4 fv[4], wv[4];
#pragma unroll
    for (int kk = 0; kk < 4; ++kk) fv[kk] = *(const float4*)&sfeat[(kq + 8 * kk) * 72 + ci];
#pragma unroll
    for (int cc = 0; cc < 4; ++cc) wv[cc] = *(const float4*)&sw[(cq + 16 * cc) * 76 + ci];
#pragma unroll
    for (int kk = 0; kk < 4; ++kk)
#pragma unroll
      for (int cc = 0; cc < 4; ++cc)
        acc[kk][cc] = dot4(acc[kk][cc], fv[kk], wv[cc]);
  }
#pragma unroll
  for (int cc = 0; cc < 4; ++cc) {
    int c = cq + 16 * cc;
    float bias = b1[c];
    float s1 = 0.f, s2 = 0.f;
#pragma unroll
    for (int kk = 0; kk < 4; ++kk) {
      float v = acc[kk][cc] + bias;
      sstage[(kq + 8 * kk) * 64 + c] = (_Float16)v;
      s1 += v; s2 += v * v;
    }
    red0[c * 8 + kq] = s1; red1[c * 8 + kq] = s2;
  }
  __syncthreads();
  if (t < 64) {
    float s1 = 0.f, s2 = 0.f;
#pragma unroll
    for (int qn = 0; qn < 8; ++qn) { s1 += red0[t * 8 + qn]; s2 += red1[t * 8 + qn]; }
    part[(size_t)g * 256 + t] = s1;
    part[(size_t)g * 256 + 64 + t] = s2;
  }
  uint4* dst = (uint4*)(pre2 + (size_t)g * 2048);
  const uint4* srcv = (const uint4*)sstage;
  dst[t] = srcv[t];
  dst[t + 128] = srcv[t + 128];
}

// ---------------------------------------------------------------------------
// Layer 2 conv — R24: MFMA f16 path. BN1+relu rounded to f16 (inputs were
// f16-stored anyway; existing absmax 0.03125 = f16 ULP at |x|~32 dominates),
// w2 rounded to f16, products f16xf16 -> f32 MFMA accumulate.
// Fragments (16x16x32, verified layouts): A[k=32][cin] lane holds
// A[l&15][kk + (l>>4)*8 + e] (contiguous half8); B[k][col] read from natural
// [c_out][c_in] storage at sw16[cbase+(l&15)][kk+(l>>4)*8+e]; C/D col=l&15,
// row=(l>>4)*4+reg -> each lane's 4 regs = 4 k-values of ONE channel, giving
// the SAME 8-partials-per-channel red0/red1/rmax/rmin shape as before; the
// proven t<128 reduction and fin_kernel are untouched. Max-over-k argument
// (relu∘BN monotone) unchanged.
// ---------------------------------------------------------------------------
__global__ __launch_bounds__(256) void convC_kernel(
    const _Float16* __restrict__ pre2, const float* __restrict__ accum,
    const float* __restrict__ gam, const float* __restrict__ bet,
    const float* __restrict__ w2, const float* __restrict__ b2,
    float* __restrict__ mm, float* __restrict__ part) {
  __shared__ __align__(16) _Float16 sfeat16[32 * 72];   // [k][cin], pad 72
  __shared__ __align__(16) _Float16 sw16[128 * 72];     // [cout][cin], pad 72
  __shared__ float red0[128 * 8], red1[128 * 8];
  __shared__ float rmax[128 * 8], rmin[128 * 8];
  __shared__ float ssc[64], ssh[64];
  int g = blockIdx.x;
  int t = threadIdx.x;
  if (t < 64) {
    float mu = accum[t] * (1.f / CNT_F);
    float var = accum[64 + t] * (1.f / CNT_F) - mu * mu;
    float sc = gam[t] / sqrtf(var + EPS_);
    ssc[t] = sc; ssh[t] = bet[t] - mu * sc;
  }
  for (int m = t; m < 2048; m += 256) {      // w2: 8192 f32 -> f16
    int c = m >> 4, ci = (m & 15) * 4;
    float4 wv = *(const float4*)&w2[m * 4];
    sw16[c * 72 + ci]     = (_Float16)wv.x;
    sw16[c * 72 + ci + 1] = (_Float16)wv.y;
    sw16[c * 72 + ci + 2] = (_Float16)wv.z;
    sw16[c * 72 + ci + 3] = (_Float16)wv.w;
  }
  __syncthreads();
  {
    const half8* src8 = (const half8*)(pre2 + (size_t)g * 2048);
    int r = t >> 3, c0 = (t & 7) * 8;        // thread owns row r, cols c0..c0+7
    half8 h0 = src8[t];
    half8 o;
#pragma unroll
    for (int e = 0; e < 8; ++e) {
      float v = (float)h0[e] * ssc[c0 + e] + ssh[c0 + e];
      o[e] = (_Float16)fmaxf(v, 0.f);
    }
    *(half8*)&sfeat16[r * 72 + c0] = o;
  }
  __syncthreads();
  int w = t >> 6, l = t & 63;
  int lg = l >> 4, lr = l & 15;
  f32x4 acc[2][2] = {};   // [mt = k-rows 0-15/16-31][ct = cout tile]
#pragma unroll
  for (int kk = 0; kk < 64; kk += 32) {
    half8 a0 = *(const half8*)&sfeat16[lr * 72 + kk + lg * 8];
    half8 a1 = *(const half8*)&sfeat16[(16 + lr) * 72 + kk + lg * 8];
    half8 bb0 = *(const half8*)&sw16[(w * 32 + lr) * 72 + kk + lg * 8];
    half8 bb1 = *(const half8*)&sw16[(w * 32 + 16 + lr) * 72 + kk + lg * 8];
    acc[0][0] = __builtin_amdgcn_mfma_f32_16x16x32_f16(a0, bb0, acc[0][0], 0, 0, 0);
    acc[0][1] = __builtin_amdgcn_mfma_f32_16x16x32_f16(a0, bb1, acc[0][1], 0, 0, 0);
    acc[1][0] = __builtin_amdgcn_mfma_f32_16x16x32_f16(a1, bb0, acc[1][0], 0, 0, 0);
    acc[1][1] = __builtin_amdgcn_mfma_f32_16x16x32_f16(a1, bb1, acc[1][1], 0, 0, 0);
  }
#pragma unroll
  for (int ct = 0; ct < 2; ++ct) {
    int c = w * 32 + ct * 16 + lr;           // this lane's channel
    float bias = b2[c];
#pragma unroll
    for (int mt = 0; mt < 2; ++mt) {
      float s1 = 0.f, s2 = 0.f, mx = -3.4e38f, mn = 3.4e38f;
#pragma unroll
      for (int r = 0; r < 4; ++r) {          // k = mt*16 + lg*4 + r
        float v = acc[mt][ct][r] + bias;
        s1 += v; s2 += v * v;
        mx = fmaxf(mx, v); mn = fminf(mn, v);
      }
      red0[c * 8 + mt * 4 + lg] = s1;
      red1[c * 8 + mt * 4 + lg] = s2;
      rmax[c * 8 + mt * 4 + lg] = mx;
      rmin[c * 8 + mt * 4 + lg] = mn;
    }
  }
  __syncthreads();
  if (t < 128) {
    float s1 = 0.f, s2 = 0.f, mx = -3.4e38f, mn = 3.4e38f;
#pragma unroll
    for (int qn = 0; qn < 8; ++qn) {
      s1 += red0[t * 8 + qn]; s2 += red1[t * 8 + qn];
      mx = fmaxf(mx, rmax[t * 8 + qn]); mn = fminf(mn, rmin[t * 8 + qn]);
    }
    part[(size_t)g * 256 + t] = s1;
    part[(size_t)g * 256 + 128 + t] = s2;
    mm[(size_t)g * 256 + t] = mx;
    mm[(size_t)g * 256 + 128 + t] = mn;
  }
}

// ---------------------------------------------------------------------------
// Final (coalesced, R8-proven): block = (b, 64-s tile); read mm rows, LDS
// transpose, write out[B,128,S] coalesced in s.
// ---------------------------------------------------------------------------
__global__ __launch_bounds__(256) void fin_kernel(
    const float* __restrict__ mm, const float* __restrict__ accum,
    const float* __restrict__ gam, const float* __restrict__ bet,
    float* __restrict__ out1) {
  __shared__ float tile[128 * 65];
  __shared__ float ssc[128], ssh[128];
  int blk = blockIdx.x;
  int b = blk >> 4;
  int s0 = (blk & 15) << 6;
  int t = threadIdx.x;
  if (t < 128) {
    float mu = accum[t] * (1.f / CNT_F);
    float var = accum[128 + t] * (1.f / CNT_F) - mu * mu;
    float sc = gam[t] / sqrtf(var + EPS_);
    ssc[t] = sc; ssh[t] = bet[t] - mu * sc;
  }
  __syncthreads();
  for (int f = t; f < 64 * 128; f += 256) {
    int sl = f >> 7, c = f & 127;
    const float* row = mm + (size_t)(b * S_ + s0 + sl) * 256;
    float sc = ssc[c];
    float v = (sc >= 0.f) ? row[c] : row[128 + c];
    tile[c * 65 + sl] = fmaxf(v * sc + ssh[c], 0.f);
  }
  __syncthreads();
  for (int f = t; f < 128 * 64; f += 256) {
    int c = f >> 6, sl = f & 63;
    out1[(size_t)b * 131072 + c * 1024 + s0 + sl] = tile[c * 65 + sl];
  }
}

// ---------------------------------------------------------------------------
extern "C" void kernel_launch(void* const* d_in, const int* in_sizes, int n_in,
                              void* d_out, int out_size, void* d_ws, size_t ws_size,
                              hipStream_t stream) {
  const float* xyz = (const float*)d_in[0];
  const float* pts = (const float*)d_in[1];
  const float* w0  = (const float*)d_in[2];
  const float* b0  = (const float*)d_in[3];
  const float* g0  = (const float*)d_in[4];
  const float* bt0 = (const float*)d_in[5];
  const float* w1  = (const float*)d_in[6];
  const float* b1  = (const float*)d_in[7];
  const float* g1  = (const float*)d_in[8];
  const float* bt1 = (const float*)d_in[9];
  const float* w2  = (const float*)d_in[10];
  const float* b2  = (const float*)d_in[11];
  const float* g2  = (const float*)d_in[12];
  const float* bt2 = (const float*)d_in[13];
  float* out = (float*)d_out;

  char* ws = (char*)d_ws;
  float*    nxyz  = (float*)(ws + OFF_NXYZ);
  float*    ptsT  = (float*)(ws + OFF_PTST);
  _Float16* pre   = (_Float16*)(ws + OFF_PRE);
  _Float16* pre2  = (_Float16*)(ws + OFF_PRE2);
  float*    part  = (float*)(ws + OFF_PART);
  float*    mm    = (float*)(ws + OFF_MM3);
  float*    accum = (float*)(ws + OFF_ACC);
  // R19-proven: bq scratch aliases PRE2 (first written by convB, strictly
  // after convA — the last segidx reader). Never PRE (R18 crash).
  int*      segidx = (int*)(ws + OFF_PRE2);
  int*      segcnt = (int*)(ws + OFF_PRE2 + 16777216u);

  (void)hipMemsetAsync(accum, 0, 3 * 256 * sizeof(float), stream);

  // Fused: blocks 0..15 = FPS (16 CUs busy), blocks 16..1039 = transpose
  // riding on the otherwise-idle 240 CUs.
  fps_tr_kernel<<<B_ + B_ * (N_ / 64), 256, 0, stream>>>(xyz, pts, nxyz, out,
                                                         ptsT);
  bq_seg_kernel<<<dim3((B_ * S_) / 64, SEG_), 64, 0, stream>>>(xyz, nxyz,
                                                               segidx, segcnt);

  convA_kernel<<<B_ * S_, 128, 0, stream>>>(ptsT, nxyz, segidx, segcnt, w0, b0,
                                            pre, part);
  red_kernel<<<256, 256, 0, stream>>>(part, accum);
  convB_kernel<<<B_ * S_, 128, 0, stream>>>(pre, accum, g0, bt0, w1, b1, pre2, part);
  red_kernel<<<256, 256, 0, stream>>>(part, accum + 256);
  convC_kernel<<<B_ * S_, 256, 0, stream>>>(pre2, accum + 256, g1, bt1, w2, b2, mm, part);
  red_kernel<<<256, 256, 0, stream>>>(part, accum + 512);
  fin_kernel<<<B_ * (S_ / 64), 256, 0, stream>>>(mm, accum + 512, g2, bt2,
                                                 out + B_ * 3 * S_);
}

// Round 14
// 1159.105 us; speedup vs baseline: 1.7692x; 1.0490x over previous
//
#include <hip/hip_runtime.h>
#include <cstdint>
#include <cstddef>

// Problem constants
#define B_    16
#define N_    4096
#define S_    1024     // NPOINT
#define K_    32       // NSAMPLE
#define CNT_F 524288.0f   // B*S*K
#define EPS_  1e-5f

// Ball-query segmentation (R14-proven): 8 index-range segments per query.
#define SEG_    8
#define SEGLEN_ (N_ / SEG_)   // 512

// Workspace layout (bytes). Total ~188 MB.
#define OFF_NXYZ 0u                    // [B][S][3] f32              196,608
#define OFF_PTST 2293760u              // [B][N][68] f32 (xyz|pts|0) 17,825,792
#define OFF_PRE  20119552u             // [BS][32][64] f16          67,108,864
#define OFF_PRE2 87228416u             // [BS][32][64] f16          67,108,864
#define OFF_PART 154337280u            // [BS][256] f32             16,777,216
#define OFF_MM3  171114496u            // [BS][2][128] f32          16,777,216
#define OFF_ACC  187891712u            // [3][256] f32                   3,072
// R19-proven: bq segment scratch lives in the PRE2 region (convB is its
// first writer, strictly after convA — the last segidx reader). Never PRE
// (convA writes pre while reading segidx -> race, R18 crash).
// R22 LESSON: do NOT replace part+red_kernel with per-block atomics — 16384
// blocks x 128-256 atomicAdds to the same words serialize at L2 (+750 us).
//   segidx [BS][SEG][K] i32 = 16,777,216 ; segcnt [BS][SEG] i32 = 524,288

typedef _Float16 half8 __attribute__((ext_vector_type(8)));
typedef float f32x4 __attribute__((ext_vector_type(4)));

// fma-chain dot4 for conv inner loops (continuous path, fma-safe).
__device__ __forceinline__ float dot4(float acc, float4 f, float4 wt) {
  return fmaf(f.w, wt.w, fmaf(f.z, wt.z, fmaf(f.y, wt.y, fmaf(f.x, wt.x, acc))));
}

// ---------------------------------------------------------------------------
// u64-key DPP max step (R17-proven). Keys are positive-f64 bit patterns
// (sign 0, exponent <= 0x3FB: never NaN/Inf/zero), so v_max_f64 ==
// lexicographic u64 max == the R8-proven comparator (max value, tie -> min
// index). Same rotation network as the proven dpp_argmax_step.
// ---------------------------------------------------------------------------
template <int CTRL, int RM>
__device__ __forceinline__ uint64_t dpp_max64(uint64_t k) {
  int lo = __builtin_amdgcn_update_dpp((int)(uint32_t)k, (int)(uint32_t)k,
                                       CTRL, RM, 0xf, false);
  int hi = __builtin_amdgcn_update_dpp((int)(uint32_t)(k >> 32),
                                       (int)(uint32_t)(k >> 32),
                                       CTRL, RM, 0xf, false);
  uint64_t o = ((uint64_t)(uint32_t)hi << 32) | (uint32_t)lo;
  double m = fmax(__longlong_as_double((long long)k),
                  __longlong_as_double((long long)o));
  return (uint64_t)__double_as_longlong(m);
}

// ---------------------------------------------------------------------------
// FPS — R17/R20-proven form (653-662 us measured, VGPR 88): u64-key
// tree/DPP, merge keys -> decode far -> sx/sy/sz[far] broadcast reads.
// 256 thr / 4 waves is this structure's optimum (R13/R21 bracketing).
// Fused transpose on blocks >= 16 (R5-proven). Selection exact (R1-R17).
// ---------------------------------------------------------------------------
__global__ __launch_bounds__(256) void fps_tr_kernel(
    const float* __restrict__ xyz, const float* __restrict__ pts,
    float* __restrict__ nxyz, float* __restrict__ out0,
    float* __restrict__ ptsT) {
#pragma clang fp contract(off)
  __shared__ __align__(16) char smem[61504];
  int t = threadIdx.x;

  if (blockIdx.x >= B_) {
    // ---------------- transpose role (R0-proven pattern) ----------------
    float* tile = (float*)smem;            // 64*69 floats = 17,664 B
    int blk = blockIdx.x - B_;
    int b = blk >> 6;
    int n0 = (blk & 63) << 6;
    int wave = t >> 6, ln = t & 63;
    int n = n0 + ln;
    for (int cc = wave; cc < 68; cc += 4) {
      float v;
      if (cc < 3)       v = xyz[(size_t)(b * 3 + cc) * N_ + n];
      else if (cc < 67) v = pts[(size_t)(b * 64 + (cc - 3)) * N_ + n];
      else              v = 0.f;
      tile[ln * 69 + cc] = v;
    }
    __syncthreads();
    for (int f = t; f < 64 * 68; f += 256) {
      int r = f / 68, c = f - r * 68;
      ptsT[(size_t)(b * N_ + n0 + r) * 68 + c] = tile[r * 69 + c];
    }
    return;
  }

  // ------------------------- FPS role (R17 verbatim) -------------------------
  float*    sx    = (float*)smem;        // [4096]
  float*    sy    = sx + N_;
  float*    sz    = sy + N_;
  float*    scent = sz + N_;             // [3072]
  uint64_t* skey  = (uint64_t*)(scent + 3 * S_);  // [2][4] (off 61440, 16B ok)

  int b = blockIdx.x;
  const float* xb = xyz + (size_t)b * 3 * N_;
  float xr[16], yr[16], zr[16], dist[16];
  uint32_t Larr[16];
#pragma unroll
  for (int j = 0; j < 16; ++j) {
    int i = j * 256 + t;                      // coalesced: lanes contiguous
    float x = xb[i], y = xb[N_ + i], z = xb[2 * N_ + i];
    xr[j] = x; yr[j] = y; zr[j] = z;
    sx[i] = x; sy[i] = y; sz[i] = z;          // bank = t%32: conflict-free
    dist[j] = 1e10f;
    // j*256 and t occupy disjoint bits -> XOR == 0x7FFFFFFF ^ (j*256+t).
    Larr[j] = 0x7FFFFFFFu ^ (uint32_t)(j * 256 + t);
  }
  __syncthreads();

  int far = 0, par = 0;
  for (int s = 0; s < S_; ++s) {
    float cx = sx[far], cy = sy[far], cz = sz[far];   // uniform broadcast read
    if (t == 0) {
      scent[s * 3]     = cx;
      scent[s * 3 + 1] = cy;
      scent[s * 3 + 2] = cz;
    }
    // Distance update (arithmetic unchanged) + key build.
    uint64_t ku[16];
#pragma unroll
    for (int j = 0; j < 16; ++j) {
      float dx = xr[j] - cx, dy = yr[j] - cy, dz = zr[j] - cz;
      float d = dx * dx + dy * dy + dz * dz;  // left-assoc, no fma
      float nd = fminf(dist[j], d);
      dist[j] = nd;
      ku[j] = ((uint64_t)__float_as_uint(nd) << 31) | Larr[j];
    }
    // Depth-4 max tree over unique keys == keep-left strict-> tree == serial
    // first-index-wins scan. Static indices -> registers.
#pragma unroll
    for (int st = 1; st < 16; st <<= 1) {
#pragma unroll
      for (int j0 = 0; j0 < 16; j0 += (st << 1)) {
        double a = __longlong_as_double((long long)ku[j0]);
        double c2 = __longlong_as_double((long long)ku[j0 + st]);
        ku[j0] = (uint64_t)__double_as_longlong(fmax(a, c2));
      }
    }
    uint64_t k = ku[0];
    // Wave max (VALU-only), winner key in lane 63 of each wave.
    k = dpp_max64<0x121, 0xf>(k);  // row_ror:1
    k = dpp_max64<0x122, 0xf>(k);  // row_ror:2
    k = dpp_max64<0x124, 0xf>(k);  // row_ror:4
    k = dpp_max64<0x128, 0xf>(k);  // row_ror:8
    k = dpp_max64<0x142, 0xa>(k);  // row_bcast15 -> rows 1,3
    k = dpp_max64<0x143, 0xc>(k);  // row_bcast31 -> rows 2,3
    if ((t & 63) == 63) skey[par * 4 + (t >> 6)] = k;
    __syncthreads();
    // Vectorized readback; u64 max over distinct keys (order-independent).
    ulonglong2 p0 = *(const ulonglong2*)&skey[par * 4];
    ulonglong2 p1 = *(const ulonglong2*)&skey[par * 4 + 2];
    uint64_t m = p0.x;
    if (p0.y > m) m = p0.y;
    if (p1.x > m) m = p1.x;
    if (p1.y > m) m = p1.y;
    far = (int)((~(uint32_t)m) & 0xFFFu);   // low 31 bits = 0x7FFFFFFF ^ idx
    par ^= 1;  // double-buffered slots -> one barrier per iteration
  }
  __syncthreads();
  // Coalesced output writes from LDS staging.
  for (int f = t; f < 3 * S_; f += 256)
    nxyz[(size_t)b * 3 * S_ + f] = scent[f];        // [B][S][3]
  for (int s = t; s < S_; s += 256) {               // [B][3][S]
    out0[(size_t)b * 3 * S_ + s]          = scent[s * 3];
    out0[(size_t)b * 3 * S_ + S_ + s]     = scent[s * 3 + 1];
    out0[(size_t)b * 3 * S_ + 2 * S_ + s] = scent[s * 3 + 2];
  }
}

// ---------------------------------------------------------------------------
// Ball query (R14-proven semantics, R19-proven float4 form): 8-way segmented
// scan; per-point fma chain, scan order, and early-exit checks IDENTICAL.
// ---------------------------------------------------------------------------
__global__ __launch_bounds__(64) void bq_seg_kernel(
    const float* __restrict__ xyz, const float* __restrict__ nxyz,
    int* __restrict__ segidx, int* __restrict__ segcnt) {
#pragma clang fp contract(off)
  int q = blockIdx.x * 64 + threadIdx.x;
  int seg = blockIdx.y;
  int b = q >> 10;
  const float* xb = xyz + (size_t)b * 3 * N_;
  float cx = nxyz[(size_t)q * 3];
  float cy = nxyz[(size_t)q * 3 + 1];
  float cz = nxyz[(size_t)q * 3 + 2];
  float A = fmaf(cz, cz, fmaf(cy, cy, cx * cx));
  int* out = segidx + ((size_t)q * SEG_ + seg) * K_;
  int found = 0;
  int i0 = seg * SEGLEN_;
#define BQ_POINT(xx, yy, zz, ii)                                   \
  {                                                                \
    float x = (xx), y = (yy), z = (zz);                            \
    float Bv  = fmaf(z, z, fmaf(y, y, x * x));                     \
    float dot = fmaf(cz, z, fmaf(cy, y, cx * x));                  \
    float d = fmaf(-2.0f, dot, A + Bv);                            \
    if (d <= 0.04f) {                                              \
      out[found] = (ii);                                           \
      ++found;                                                     \
      if (found >= K_) goto done;                                  \
    }                                                              \
  }
  for (int i = i0; i < i0 + SEGLEN_; i += 4) {
    float4 xv = *(const float4*)&xb[i];
    float4 yv = *(const float4*)&xb[N_ + i];
    float4 zv = *(const float4*)&xb[2 * N_ + i];
    BQ_POINT(xv.x, yv.x, zv.x, i)
    BQ_POINT(xv.y, yv.y, zv.y, i + 1)
    BQ_POINT(xv.z, yv.z, zv.z, i + 2)
    BQ_POINT(xv.w, yv.w, zv.w, i + 3)
  }
done:
  segcnt[q * SEG_ + seg] = found;
#undef BQ_POINT
}

// ---------------------------------------------------------------------------
// Layer 0 conv (tiled, validated) with the bq MERGE FUSED IN (R19-proven):
// thread k<32 computes the k-th element of the in-order segment concatenation
// via an unrolled prefix chain (exactly bq_merge's semantics); fill = rank-0
// element (always exists: centroid's own d == 0 exactly). Gather/dot/stats
// unchanged (R16-proven). Stays f32 (input ptsT is f32; f16-casting the
// FIRST layer would inject error amplified through 2 more layers).
// ---------------------------------------------------------------------------
__global__ __launch_bounds__(128) void convA_kernel(
    const float* __restrict__ ptsT, const float* __restrict__ nxyz,
    const int* __restrict__ segidx, const int* __restrict__ segcnt,
    const float* __restrict__ w0, const float* __restrict__ b0,
    _Float16* __restrict__ pre, float* __restrict__ part) {
  __shared__ __align__(16) float sfeat[32 * 72];
  __shared__ __align__(16) float sw[64 * 76];
  __shared__ float red0[64 * 8], red1[64 * 8];
  __shared__ __align__(16) _Float16 sstage[2048];
  __shared__ int sidx[32];
  __shared__ int scnt[8];
  int g = blockIdx.x;
  int t = threadIdx.x;
  int b = g >> 10;
  if (t < 8) scnt[t] = segcnt[(size_t)g * SEG_ + t];
  for (int f = t; f < 64 * 68; f += 128) {
    int c = f / 68, ci = f - c * 68;
    sw[c * 76 + ci] = (ci < 67) ? w0[c * 67 + ci] : 0.f;
  }
  const float* nx = nxyz + (size_t)g * 3;
  float ctr0 = nx[0], ctr1 = nx[1], ctr2 = nx[2];
  __syncthreads();
  if (t < 32) {
    int c0 = scnt[0], c1 = scnt[1], c2 = scnt[2], c3 = scnt[3];
    int c4 = scnt[4], c5 = scnt[5], c6 = scnt[6], c7 = scnt[7];
    int r = t, sel = -1, off = 0;
#define MSTEP(cs, s)                                  \
    if (sel < 0) {                                    \
      if (r < (cs)) { sel = (s); off = r; }           \
      else r -= (cs);                                 \
    }
    MSTEP(c0, 0) MSTEP(c1, 1) MSTEP(c2, 2) MSTEP(c3, 3)
    MSTEP(c4, 4) MSTEP(c5, 5) MSTEP(c6, 6) MSTEP(c7, 7)
#undef MSTEP
    // First non-empty segment (rank-0 source) for the fill value.
    int f0 = (c0 > 0) ? 0 : (c1 > 0) ? 1 : (c2 > 0) ? 2 : (c3 > 0) ? 3
           : (c4 > 0) ? 4 : (c5 > 0) ? 5 : (c6 > 0) ? 6 : 7;
    int sseg = (sel >= 0) ? sel : f0;
    int soff = (sel >= 0) ? off : 0;
    sidx[t] = segidx[((size_t)g * SEG_ + sseg) * K_ + soff];
  }
  __syncthreads();
  for (int f = t; f < 32 * 17; f += 128) {   // 17 float4 per 68-col row
    int k = f / 17, q = f - k * 17;
    float4 v = *(const float4*)&ptsT[(size_t)(b * N_ + sidx[k]) * 68 + q * 4];
    if (q == 0) { v.x -= ctr0; v.y -= ctr1; v.z -= ctr2; }
    *(float4*)&sfeat[k * 72 + q * 4] = v;
  }
  __syncthreads();
  int kq = t & 7, cq = t >> 3;
  float acc[4][4] = {};
  for (int ci = 0; ci < 68; ci += 4) {
    float4 fv[4], wv[4];
#pragma unroll
    for (int kk = 0; kk < 4; ++kk) fv[kk] = *(const float4*)&sfeat[(kq + 8 * kk) * 72 + ci];
#pragma unroll
    for (int cc = 0; cc < 4; ++cc) wv[cc] = *(const float4*)&sw[(cq + 16 * cc) * 76 + ci];
#pragma unroll
    for (int kk = 0; kk < 4; ++kk)
#pragma unroll
      for (int cc = 0; cc < 4; ++cc)
        acc[kk][cc] = dot4(acc[kk][cc], fv[kk], wv[cc]);
  }
#pragma unroll
  for (int cc = 0; cc < 4; ++cc) {
    int c = cq + 16 * cc;
    float bias = b0[c];
    float s1 = 0.f, s2 = 0.f;
#pragma unroll
    for (int kk = 0; kk < 4; ++kk) {
      float v = acc[kk][cc] + bias;
      sstage[(kq + 8 * kk) * 64 + c] = (_Float16)v;
      s1 += v; s2 += v * v;
    }
    red0[c * 8 + kq] = s1; red1[c * 8 + kq] = s2;
  }
  __syncthreads();
  if (t < 64) {
    float s1 = 0.f, s2 = 0.f;
#pragma unroll
    for (int qn = 0; qn < 8; ++qn) { s1 += red0[t * 8 + qn]; s2 += red1[t * 8 + qn]; }
    part[(size_t)g * 256 + t] = s1;
    part[(size_t)g * 256 + 64 + t] = s2;
  }
  uint4* dst = (uint4*)(pre + (size_t)g * 2048);
  const uint4* srcv = (const uint4*)sstage;
  dst[t] = srcv[t];
  dst[t + 128] = srcv[t + 128];
}

// ---------------------------------------------------------------------------
// Stats reduce (coalesced, R8-proven): thread t owns channel t; block sums 64
// consecutive rows; one atomicAdd per (block, channel). accum pre-zeroed.
// R22 lesson: this two-level scheme (64-row in-register sum, then ONE atomic
// per block-channel) is required — direct per-conv-block atomics serialize.
// ---------------------------------------------------------------------------
__global__ __launch_bounds__(256) void red_kernel(
    const float* __restrict__ part, float* __restrict__ accum) {
  int t = threadIdx.x;
  size_t base = (size_t)blockIdx.x * 64 * 256 + t;
  float a = 0.f;
#pragma unroll 8
  for (int r = 0; r < 64; ++r) a += part[base + (size_t)r * 256];
  atomicAdd(accum + t, a);
}

// ---------------------------------------------------------------------------
// Layer 1 conv — R25: MFMA f16 path (R24's proven convC pattern ported,
// c_out=64, 128 thr = 2 waves x 32 channels). BN0+relu rounded to f16
// (inputs f16-stored anyway), w1 rounded to f16, f32 MFMA accumulate.
// Fragments (16x16x32, verified layouts): A lane holds A[l&15][kk+(l>>4)*8+e]
// (contiguous half8); B from natural [c_out][c_in] at
// sw16[cbase+(l&15)][kk+(l>>4)*8+e]; C/D col=l&15, row=(l>>4)*4+reg ->
// lane's 4 regs = 4 k-values of ONE channel -> same 8-partials-per-channel
// red0/red1 shape; t<64 reduction + pre2 copy untouched. sstage write:
// lane writes its 4 k-rows at sstage[k*64+c] (16 lanes span 16 consecutive
// channels -> contiguous 32B groups).
// ---------------------------------------------------------------------------
__global__ __launch_bounds__(128) void convB_kernel(
    const _Float16* __restrict__ pre, const float* __restrict__ accum,
    const float* __restrict__ gam, const float* __restrict__ bet,
    const float* __restrict__ w1, const float* __restrict__ b1,
    _Float16* __restrict__ pre2, float* __restrict__ part) {
  __shared__ __align__(16) _Float16 sfeat16[32 * 72];   // [k][cin], pad 72
  __shared__ __align__(16) _Float16 sw16[64 * 72];      // [cout][cin], pad 72
  __shared__ float red0[64 * 8], red1[64 * 8];
  __shared__ __align__(16) _Float16 sstage[2048];
  __shared__ float ssc[64], ssh[64];
  int g = blockIdx.x;
  int t = threadIdx.x;
  if (t < 64) {
    float mu = accum[t] * (1.f / CNT_F);
    float var = accum[64 + t] * (1.f / CNT_F) - mu * mu;
    float sc = gam[t] / sqrtf(var + EPS_);
    ssc[t] = sc; ssh[t] = bet[t] - mu * sc;
  }
  for (int m = t; m < 1024; m += 128) {      // w1: 4096 f32 -> f16
    int c = m >> 4, ci = (m & 15) * 4;
    float4 wv = *(const float4*)&w1[m * 4];
    sw16[c * 72 + ci]     = (_Float16)wv.x;
    sw16[c * 72 + ci + 1] = (_Float16)wv.y;
    sw16[c * 72 + ci + 2] = (_Float16)wv.z;
    sw16[c * 72 + ci + 3] = (_Float16)wv.w;
  }
  __syncthreads();
  {
    const half8* src8 = (const half8*)(pre + (size_t)g * 2048);
    int r = t >> 2, c0 = (t & 3) * 16;       // thread owns row r, cols c0..c0+15
    half8 h0 = src8[t * 2], h1 = src8[t * 2 + 1];
    half8 o0, o1;
#pragma unroll
    for (int e = 0; e < 8; ++e) {
      float v = (float)h0[e] * ssc[c0 + e] + ssh[c0 + e];
      o0[e] = (_Float16)fmaxf(v, 0.f);
    }
#pragma unroll
    for (int e = 0; e < 8; ++e) {
      float v = (float)h1[e] * ssc[c0 + 8 + e] + ssh[c0 + 8 + e];
      o1[e] = (_Float16)fmaxf(v, 0.f);
    }
    *(half8*)&sfeat16[r * 72 + c0] = o0;
    *(half8*)&sfeat16[r * 72 + c0 + 8] = o1;
  }
  __syncthreads();
  int w = t >> 6, l = t & 63;                // 2 waves: w in {0,1}
  int lg = l >> 4, lr = l & 15;
  f32x4 acc[2][2] = {};   // [mt = k-rows 0-15/16-31][ct = cout tile]
#pragma unroll
  for (int kk = 0; kk < 64; kk += 32) {
    half8 a0 = *(const half8*)&sfeat16[lr * 72 + kk + lg * 8];
    half8 a1 = *(const half8*)&sfeat16[(16 + lr) * 72 + kk + lg * 8];
    half8 bb0 = *(const half8*)&sw16[(w * 32 + lr) * 72 + kk + lg * 8];
    half8 bb1 = *(const half8*)&sw16[(w * 32 + 16 + lr) * 72 + kk + lg * 8];
    acc[0][0] = __builtin_amdgcn_mfma_f32_16x16x32_f16(a0, bb0, acc[0][0], 0, 0, 0);
    acc[0][1] = __builtin_amdgcn_mfma_f32_16x16x32_f16(a0, bb1, acc[0][1], 0, 0, 0);
    acc[1][0] = __builtin_amdgcn_mfma_f32_16x16x32_f16(a1, bb0, acc[1][0], 0, 0, 0);
    acc[1][1] = __builtin_amdgcn_mfma_f32_16x16x32_f16(a1, bb1, acc[1][1], 0, 0, 0);
  }
#pragma unroll
  for (int ct = 0; ct < 2; ++ct) {
    int c = w * 32 + ct * 16 + lr;           // this lane's channel
    float bias = b1[c];
#pragma unroll
    for (int mt = 0; mt < 2; ++mt) {
      float s1 = 0.f, s2 = 0.f;
#pragma unroll
      for (int r = 0; r < 4; ++r) {          // k = mt*16 + lg*4 + r
        float v = acc[mt][ct][r] + bias;
        sstage[(mt * 16 + lg * 4 + r) * 64 + c] = (_Float16)v;
        s1 += v; s2 += v * v;
      }
      red0[c * 8 + mt * 4 + lg] = s1;
      red1[c * 8 + mt * 4 + lg] = s2;
    }
  }
  __syncthreads();
  if (t < 64) {
    float s1 = 0.f, s2 = 0.f;
#pragma unroll
    for (int qn = 0; qn < 8; ++qn) { s1 += red0[t * 8 + qn]; s2 += red1[t * 8 + qn]; }
    part[(size_t)g * 256 + t] = s1;
    part[(size_t)g * 256 + 64 + t] = s2;
  }
  uint4* dst = (uint4*)(pre2 + (size_t)g * 2048);
  const uint4* srcv = (const uint4*)sstage;
  dst[t] = srcv[t];
  dst[t + 128] = srcv[t + 128];
}

// ---------------------------------------------------------------------------
// Layer 2 conv — R24-proven MFMA f16 path. See R24 comment: fragment layouts
// verified; epilogue shape identical to pre-MFMA scheme; max-over-k argument
// (relu∘BN monotone) unchanged.
// ---------------------------------------------------------------------------
__global__ __launch_bounds__(256) void convC_kernel(
    const _Float16* __restrict__ pre2, const float* __restrict__ accum,
    const float* __restrict__ gam, const float* __restrict__ bet,
    const float* __restrict__ w2, const float* __restrict__ b2,
    float* __restrict__ mm, float* __restrict__ part) {
  __shared__ __align__(16) _Float16 sfeat16[32 * 72];   // [k][cin], pad 72
  __shared__ __align__(16) _Float16 sw16[128 * 72];     // [cout][cin], pad 72
  __shared__ float red0[128 * 8], red1[128 * 8];
  __shared__ float rmax[128 * 8], rmin[128 * 8];
  __shared__ float ssc[64], ssh[64];
  int g = blockIdx.x;
  int t = threadIdx.x;
  if (t < 64) {
    float mu = accum[t] * (1.f / CNT_F);
    float var = accum[64 + t] * (1.f / CNT_F) - mu * mu;
    float sc = gam[t] / sqrtf(var + EPS_);
    ssc[t] = sc; ssh[t] = bet[t] - mu * sc;
  }
  for (int m = t; m < 2048; m += 256) {      // w2: 8192 f32 -> f16
    int c = m >> 4, ci = (m & 15) * 4;
    float4 wv = *(const float4*)&w2[m * 4];
    sw16[c * 72 + ci]     = (_Float16)wv.x;
    sw16[c * 72 + ci + 1] = (_Float16)wv.y;
    sw16[c * 72 + ci + 2] = (_Float16)wv.z;
    sw16[c * 72 + ci + 3] = (_Float16)wv.w;
  }
  __syncthreads();
  {
    const half8* src8 = (const half8*)(pre2 + (size_t)g * 2048);
    int r = t >> 3, c0 = (t & 7) * 8;        // thread owns row r, cols c0..c0+7
    half8 h0 = src8[t];
    half8 o;
#pragma unroll
    for (int e = 0; e < 8; ++e) {
      float v = (float)h0[e] * ssc[c0 + e] + ssh[c0 + e];
      o[e] = (_Float16)fmaxf(v, 0.f);
    }
    *(half8*)&sfeat16[r * 72 + c0] = o;
  }
  __syncthreads();
  int w = t >> 6, l = t & 63;
  int lg = l >> 4, lr = l & 15;
  f32x4 acc[2][2] = {};   // [mt = k-rows 0-15/16-31][ct = cout tile]
#pragma unroll
  for (int kk = 0; kk < 64; kk += 32) {
    half8 a0 = *(const half8*)&sfeat16[lr * 72 + kk + lg * 8];
    half8 a1 = *(const half8*)&sfeat16[(16 + lr) * 72 + kk + lg * 8];
    half8 bb0 = *(const half8*)&sw16[(w * 32 + lr) * 72 + kk + lg * 8];
    half8 bb1 = *(const half8*)&sw16[(w * 32 + 16 + lr) * 72 + kk + lg * 8];
    acc[0][0] = __builtin_amdgcn_mfma_f32_16x16x32_f16(a0, bb0, acc[0][0], 0, 0, 0);
    acc[0][1] = __builtin_amdgcn_mfma_f32_16x16x32_f16(a0, bb1, acc[0][1], 0, 0, 0);
    acc[1][0] = __builtin_amdgcn_mfma_f32_16x16x32_f16(a1, bb0, acc[1][0], 0, 0, 0);
    acc[1][1] = __builtin_amdgcn_mfma_f32_16x16x32_f16(a1, bb1, acc[1][1], 0, 0, 0);
  }
#pragma unroll
  for (int ct = 0; ct < 2; ++ct) {
    int c = w * 32 + ct * 16 + lr;           // this lane's channel
    float bias = b2[c];
#pragma unroll
    for (int mt = 0; mt < 2; ++mt) {
      float s1 = 0.f, s2 = 0.f, mx = -3.4e38f, mn = 3.4e38f;
#pragma unroll
      for (int r = 0; r < 4; ++r) {          // k = mt*16 + lg*4 + r
        float v = acc[mt][ct][r] + bias;
        s1 += v; s2 += v * v;
        mx = fmaxf(mx, v); mn = fminf(mn, v);
      }
      red0[c * 8 + mt * 4 + lg] = s1;
      red1[c * 8 + mt * 4 + lg] = s2;
      rmax[c * 8 + mt * 4 + lg] = mx;
      rmin[c * 8 + mt * 4 + lg] = mn;
    }
  }
  __syncthreads();
  if (t < 128) {
    float s1 = 0.f, s2 = 0.f, mx = -3.4e38f, mn = 3.4e38f;
#pragma unroll
    for (int qn = 0; qn < 8; ++qn) {
      s1 += red0[t * 8 + qn]; s2 += red1[t * 8 + qn];
      mx = fmaxf(mx, rmax[t * 8 + qn]); mn = fminf(mn, rmin[t * 8 + qn]);
    }
    part[(size_t)g * 256 + t] = s1;
    part[(size_t)g * 256 + 128 + t] = s2;
    mm[(size_t)g * 256 + t] = mx;
    mm[(size_t)g * 256 + 128 + t] = mn;
  }
}

// ---------------------------------------------------------------------------
// Final (coalesced, R8-proven): block = (b, 64-s tile); read mm rows, LDS
// transpose, write out[B,128,S] coalesced in s.
// ---------------------------------------------------------------------------
__global__ __launch_bounds__(256) void fin_kernel(
    const float* __restrict__ mm, const float* __restrict__ accum,
    const float* __restrict__ gam, const float* __restrict__ bet,
    float* __restrict__ out1) {
  __shared__ float tile[128 * 65];
  __shared__ float ssc[128], ssh[128];
  int blk = blockIdx.x;
  int b = blk >> 4;
  int s0 = (blk & 15) << 6;
  int t = threadIdx.x;
  if (t < 128) {
    float mu = accum[t] * (1.f / CNT_F);
    float var = accum[128 + t] * (1.f / CNT_F) - mu * mu;
    float sc = gam[t] / sqrtf(var + EPS_);
    ssc[t] = sc; ssh[t] = bet[t] - mu * sc;
  }
  __syncthreads();
  for (int f = t; f < 64 * 128; f += 256) {
    int sl = f >> 7, c = f & 127;
    const float* row = mm + (size_t)(b * S_ + s0 + sl) * 256;
    float sc = ssc[c];
    float v = (sc >= 0.f) ? row[c] : row[128 + c];
    tile[c * 65 + sl] = fmaxf(v * sc + ssh[c], 0.f);
  }
  __syncthreads();
  for (int f = t; f < 128 * 64; f += 256) {
    int c = f >> 6, sl = f & 63;
    out1[(size_t)b * 131072 + c * 1024 + s0 + sl] = tile[c * 65 + sl];
  }
}

// ---------------------------------------------------------------------------
extern "C" void kernel_launch(void* const* d_in, const int* in_sizes, int n_in,
                              void* d_out, int out_size, void* d_ws, size_t ws_size,
                              hipStream_t stream) {
  const float* xyz = (const float*)d_in[0];
  const float* pts = (const float*)d_in[1];
  const float* w0  = (const float*)d_in[2];
  const float* b0  = (const float*)d_in[3];
  const float* g0  = (const float*)d_in[4];
  const float* bt0 = (const float*)d_in[5];
  const float* w1  = (const float*)d_in[6];
  const float* b1  = (const float*)d_in[7];
  const float* g1  = (const float*)d_in[8];
  const float* bt1 = (const float*)d_in[9];
  const float* w2  = (const float*)d_in[10];
  const float* b2  = (const float*)d_in[11];
  const float* g2  = (const float*)d_in[12];
  const float* bt2 = (const float*)d_in[13];
  float* out = (float*)d_out;

  char* ws = (char*)d_ws;
  float*    nxyz  = (float*)(ws + OFF_NXYZ);
  float*    ptsT  = (float*)(ws + OFF_PTST);
  _Float16* pre   = (_Float16*)(ws + OFF_PRE);
  _Float16* pre2  = (_Float16*)(ws + OFF_PRE2);
  float*    part  = (float*)(ws + OFF_PART);
  float*    mm    = (float*)(ws + OFF_MM3);
  float*    accum = (float*)(ws + OFF_ACC);
  // R19-proven: bq scratch aliases PRE2 (first written by convB, strictly
  // after convA — the last segidx reader). Never PRE (R18 crash).
  int*      segidx = (int*)(ws + OFF_PRE2);
  int*      segcnt = (int*)(ws + OFF_PRE2 + 16777216u);

  (void)hipMemsetAsync(accum, 0, 3 * 256 * sizeof(float), stream);

  // Fused: blocks 0..15 = FPS (16 CUs busy), blocks 16..1039 = transpose
  // riding on the otherwise-idle 240 CUs.
  fps_tr_kernel<<<B_ + B_ * (N_ / 64), 256, 0, stream>>>(xyz, pts, nxyz, out,
                                                         ptsT);
  bq_seg_kernel<<<dim3((B_ * S_) / 64, SEG_), 64, 0, stream>>>(xyz, nxyz,
                                                               segidx, segcnt);

  convA_kernel<<<B_ * S_, 128, 0, stream>>>(ptsT, nxyz, segidx, segcnt, w0, b0,
                                            pre, part);
  red_kernel<<<256, 256, 0, stream>>>(part, accum);
  convB_kernel<<<B_ * S_, 128, 0, stream>>>(pre, accum, g0, bt0, w1, b1, pre2, part);
  red_kernel<<<256, 256, 0, stream>>>(part, accum + 256);
  convC_kernel<<<B_ * S_, 256, 0, stream>>>(pre2, accum + 256, g1, bt1, w2, b2, mm, part);
  red_kernel<<<256, 256, 0, stream>>>(part, accum + 512);
  fin_kernel<<<B_ * (S_ / 64), 256, 0, stream>>>(mm, accum + 512, g2, bt2,
                                                 out + B_ * 3 * S_);
}

// Round 15
// 1131.733 us; speedup vs baseline: 1.8120x; 1.0242x over previous
//
#include <hip/hip_runtime.h>
#include <cstdint>
#include <cstddef>

// Problem constants
#define B_    16
#define N_    4096
#define S_    1024     // NPOINT
#define K_    32       // NSAMPLE
#define CNT_F 524288.0f   // B*S*K
#define EPS_  1e-5f

// Ball-query segmentation (R14-proven): 8 index-range segments per query.
#define SEG_    8
#define SEGLEN_ (N_ / SEG_)   // 512

// Workspace layout (bytes). Total ~188 MB.
#define OFF_NXYZ 0u                    // [B][S][3] f32              196,608
#define OFF_PTST 2293760u              // [B][N][68] f32 (xyz|pts|0) 17,825,792
#define OFF_PRE  20119552u             // [BS][32][64] f16          67,108,864
#define OFF_PRE2 87228416u             // [BS][32][64] f16          67,108,864
#define OFF_PART 154337280u            // [BS][256] f32             16,777,216
#define OFF_MM3  171114496u            // [BS][2][128] f32          16,777,216
#define OFF_ACC  187891712u            // [3][256] f32                   3,072
// R19-proven: bq segment scratch lives in the PRE2 region (convB is its
// first writer, strictly after convA — the last segidx reader). Never PRE
// (convA writes pre while reading segidx -> race, R18 crash).
// R22 LESSON: do NOT replace part+red_kernel with per-block atomics — 16384
// blocks x 128-256 atomicAdds to the same words serialize at L2 (+750 us).
//   segidx [BS][SEG][K] i32 = 16,777,216 ; segcnt [BS][SEG] i32 = 524,288

typedef _Float16 half8 __attribute__((ext_vector_type(8)));
typedef _Float16 half4 __attribute__((ext_vector_type(4)));
typedef float f32x4 __attribute__((ext_vector_type(4)));

// ---------------------------------------------------------------------------
// u64-key DPP max step (R17-proven). Keys are positive-f64 bit patterns
// (sign 0, exponent <= 0x3FB: never NaN/Inf/zero), so v_max_f64 ==
// lexicographic u64 max == the R8-proven comparator (max value, tie -> min
// index). Same rotation network as the proven dpp_argmax_step.
// ---------------------------------------------------------------------------
template <int CTRL, int RM>
__device__ __forceinline__ uint64_t dpp_max64(uint64_t k) {
  int lo = __builtin_amdgcn_update_dpp((int)(uint32_t)k, (int)(uint32_t)k,
                                       CTRL, RM, 0xf, false);
  int hi = __builtin_amdgcn_update_dpp((int)(uint32_t)(k >> 32),
                                       (int)(uint32_t)(k >> 32),
                                       CTRL, RM, 0xf, false);
  uint64_t o = ((uint64_t)(uint32_t)hi << 32) | (uint32_t)lo;
  double m = fmax(__longlong_as_double((long long)k),
                  __longlong_as_double((long long)o));
  return (uint64_t)__double_as_longlong(m);
}

// ---------------------------------------------------------------------------
// FPS — R17/R20-proven form (653-662 us measured, VGPR 88): u64-key
// tree/DPP, merge keys -> decode far -> sx/sy/sz[far] broadcast reads.
// 256 thr / 4 waves is this structure's optimum (R13/R21 bracketing).
// Fused transpose on blocks >= 16 (R5-proven). Selection exact (R1-R17).
// ---------------------------------------------------------------------------
__global__ __launch_bounds__(256) void fps_tr_kernel(
    const float* __restrict__ xyz, const float* __restrict__ pts,
    float* __restrict__ nxyz, float* __restrict__ out0,
    float* __restrict__ ptsT) {
#pragma clang fp contract(off)
  __shared__ __align__(16) char smem[61504];
  int t = threadIdx.x;

  if (blockIdx.x >= B_) {
    // ---------------- transpose role (R0-proven pattern) ----------------
    float* tile = (float*)smem;            // 64*69 floats = 17,664 B
    int blk = blockIdx.x - B_;
    int b = blk >> 6;
    int n0 = (blk & 63) << 6;
    int wave = t >> 6, ln = t & 63;
    int n = n0 + ln;
    for (int cc = wave; cc < 68; cc += 4) {
      float v;
      if (cc < 3)       v = xyz[(size_t)(b * 3 + cc) * N_ + n];
      else if (cc < 67) v = pts[(size_t)(b * 64 + (cc - 3)) * N_ + n];
      else              v = 0.f;
      tile[ln * 69 + cc] = v;
    }
    __syncthreads();
    for (int f = t; f < 64 * 68; f += 256) {
      int r = f / 68, c = f - r * 68;
      ptsT[(size_t)(b * N_ + n0 + r) * 68 + c] = tile[r * 69 + c];
    }
    return;
  }

  // ------------------------- FPS role (R17 verbatim) -------------------------
  float*    sx    = (float*)smem;        // [4096]
  float*    sy    = sx + N_;
  float*    sz    = sy + N_;
  float*    scent = sz + N_;             // [3072]
  uint64_t* skey  = (uint64_t*)(scent + 3 * S_);  // [2][4] (off 61440, 16B ok)

  int b = blockIdx.x;
  const float* xb = xyz + (size_t)b * 3 * N_;
  float xr[16], yr[16], zr[16], dist[16];
  uint32_t Larr[16];
#pragma unroll
  for (int j = 0; j < 16; ++j) {
    int i = j * 256 + t;                      // coalesced: lanes contiguous
    float x = xb[i], y = xb[N_ + i], z = xb[2 * N_ + i];
    xr[j] = x; yr[j] = y; zr[j] = z;
    sx[i] = x; sy[i] = y; sz[i] = z;          // bank = t%32: conflict-free
    dist[j] = 1e10f;
    // j*256 and t occupy disjoint bits -> XOR == 0x7FFFFFFF ^ (j*256+t).
    Larr[j] = 0x7FFFFFFFu ^ (uint32_t)(j * 256 + t);
  }
  __syncthreads();

  int far = 0, par = 0;
  for (int s = 0; s < S_; ++s) {
    float cx = sx[far], cy = sy[far], cz = sz[far];   // uniform broadcast read
    if (t == 0) {
      scent[s * 3]     = cx;
      scent[s * 3 + 1] = cy;
      scent[s * 3 + 2] = cz;
    }
    // Distance update (arithmetic unchanged) + key build.
    uint64_t ku[16];
#pragma unroll
    for (int j = 0; j < 16; ++j) {
      float dx = xr[j] - cx, dy = yr[j] - cy, dz = zr[j] - cz;
      float d = dx * dx + dy * dy + dz * dz;  // left-assoc, no fma
      float nd = fminf(dist[j], d);
      dist[j] = nd;
      ku[j] = ((uint64_t)__float_as_uint(nd) << 31) | Larr[j];
    }
    // Depth-4 max tree over unique keys == keep-left strict-> tree == serial
    // first-index-wins scan. Static indices -> registers.
#pragma unroll
    for (int st = 1; st < 16; st <<= 1) {
#pragma unroll
      for (int j0 = 0; j0 < 16; j0 += (st << 1)) {
        double a = __longlong_as_double((long long)ku[j0]);
        double c2 = __longlong_as_double((long long)ku[j0 + st]);
        ku[j0] = (uint64_t)__double_as_longlong(fmax(a, c2));
      }
    }
    uint64_t k = ku[0];
    // Wave max (VALU-only), winner key in lane 63 of each wave.
    k = dpp_max64<0x121, 0xf>(k);  // row_ror:1
    k = dpp_max64<0x122, 0xf>(k);  // row_ror:2
    k = dpp_max64<0x124, 0xf>(k);  // row_ror:4
    k = dpp_max64<0x128, 0xf>(k);  // row_ror:8
    k = dpp_max64<0x142, 0xa>(k);  // row_bcast15 -> rows 1,3
    k = dpp_max64<0x143, 0xc>(k);  // row_bcast31 -> rows 2,3
    if ((t & 63) == 63) skey[par * 4 + (t >> 6)] = k;
    __syncthreads();
    // Vectorized readback; u64 max over distinct keys (order-independent).
    ulonglong2 p0 = *(const ulonglong2*)&skey[par * 4];
    ulonglong2 p1 = *(const ulonglong2*)&skey[par * 4 + 2];
    uint64_t m = p0.x;
    if (p0.y > m) m = p0.y;
    if (p1.x > m) m = p1.x;
    if (p1.y > m) m = p1.y;
    far = (int)((~(uint32_t)m) & 0xFFFu);   // low 31 bits = 0x7FFFFFFF ^ idx
    par ^= 1;  // double-buffered slots -> one barrier per iteration
  }
  __syncthreads();
  // Coalesced output writes from LDS staging.
  for (int f = t; f < 3 * S_; f += 256)
    nxyz[(size_t)b * 3 * S_ + f] = scent[f];        // [B][S][3]
  for (int s = t; s < S_; s += 256) {               // [B][3][S]
    out0[(size_t)b * 3 * S_ + s]          = scent[s * 3];
    out0[(size_t)b * 3 * S_ + S_ + s]     = scent[s * 3 + 1];
    out0[(size_t)b * 3 * S_ + 2 * S_ + s] = scent[s * 3 + 2];
  }
}

// ---------------------------------------------------------------------------
// Ball query (R14-proven semantics, R19-proven float4 form): 8-way segmented
// scan; per-point fma chain, scan order, and early-exit checks IDENTICAL.
// ---------------------------------------------------------------------------
__global__ __launch_bounds__(64) void bq_seg_kernel(
    const float* __restrict__ xyz, const float* __restrict__ nxyz,
    int* __restrict__ segidx, int* __restrict__ segcnt) {
#pragma clang fp contract(off)
  int q = blockIdx.x * 64 + threadIdx.x;
  int seg = blockIdx.y;
  int b = q >> 10;
  const float* xb = xyz + (size_t)b * 3 * N_;
  float cx = nxyz[(size_t)q * 3];
  float cy = nxyz[(size_t)q * 3 + 1];
  float cz = nxyz[(size_t)q * 3 + 2];
  float A = fmaf(cz, cz, fmaf(cy, cy, cx * cx));
  int* out = segidx + ((size_t)q * SEG_ + seg) * K_;
  int found = 0;
  int i0 = seg * SEGLEN_;
#define BQ_POINT(xx, yy, zz, ii)                                   \
  {                                                                \
    float x = (xx), y = (yy), z = (zz);                            \
    float Bv  = fmaf(z, z, fmaf(y, y, x * x));                     \
    float dot = fmaf(cz, z, fmaf(cy, y, cx * x));                  \
    float d = fmaf(-2.0f, dot, A + Bv);                            \
    if (d <= 0.04f) {                                              \
      out[found] = (ii);                                           \
      ++found;                                                     \
      if (found >= K_) goto done;                                  \
    }                                                              \
  }
  for (int i = i0; i < i0 + SEGLEN_; i += 4) {
    float4 xv = *(const float4*)&xb[i];
    float4 yv = *(const float4*)&xb[N_ + i];
    float4 zv = *(const float4*)&xb[2 * N_ + i];
    BQ_POINT(xv.x, yv.x, zv.x, i)
    BQ_POINT(xv.y, yv.y, zv.y, i + 1)
    BQ_POINT(xv.z, yv.z, zv.z, i + 2)
    BQ_POINT(xv.w, yv.w, zv.w, i + 3)
  }
done:
  segcnt[q * SEG_ + seg] = found;
#undef BQ_POINT
}

// ---------------------------------------------------------------------------
// Layer 0 conv — R26: MFMA f16 path (third application of the R24/R25-proven
// pattern). K padded 68 -> 96 (3 k-steps of 32); pad columns are ZERO in both
// A and B -> contribute exactly 0. Gather converts to f16 at LDS-write time
// (centroid subtract still f32 before the cast); w0 rounded to f16.
// Numerics: f16 input rounding ~5e-4 rel on unit-scale values, final-output
// perturbation ~1e-2 vs the 15-round-stable 0.03125 f16-storage grain.
// bq MERGE FUSED (R19-proven) unchanged. Epilogue = R25 convB shape
// (lane's 4 regs = 4 k-values of one channel; red0/red1 + sstage identical).
// ---------------------------------------------------------------------------
__global__ __launch_bounds__(128) void convA_kernel(
    const float* __restrict__ ptsT, const float* __restrict__ nxyz,
    const int* __restrict__ segidx, const int* __restrict__ segcnt,
    const float* __restrict__ w0, const float* __restrict__ b0,
    _Float16* __restrict__ pre, float* __restrict__ part) {
  __shared__ __align__(16) _Float16 sfeat16[32 * 104];  // [k][cin 0..95] pad 104
  __shared__ __align__(16) _Float16 sw16[64 * 104];     // [cout][cin] pad 104
  __shared__ float red0[64 * 8], red1[64 * 8];
  __shared__ __align__(16) _Float16 sstage[2048];
  __shared__ int sidx[32];
  __shared__ int scnt[8];
  int g = blockIdx.x;
  int t = threadIdx.x;
  int b = g >> 10;
  if (t < 8) scnt[t] = segcnt[(size_t)g * SEG_ + t];
  for (int f = t; f < 64 * 96; f += 128) {   // w0 -> f16, cols 67..95 zero
    int c = f / 96, ci = f - c * 96;
    sw16[c * 104 + ci] = (ci < 67) ? (_Float16)w0[c * 67 + ci] : (_Float16)0.f;
  }
  const float* nx = nxyz + (size_t)g * 3;
  float ctr0 = nx[0], ctr1 = nx[1], ctr2 = nx[2];
  __syncthreads();
  if (t < 32) {
    int c0 = scnt[0], c1 = scnt[1], c2 = scnt[2], c3 = scnt[3];
    int c4 = scnt[4], c5 = scnt[5], c6 = scnt[6], c7 = scnt[7];
    int r = t, sel = -1, off = 0;
#define MSTEP(cs, s)                                  \
    if (sel < 0) {                                    \
      if (r < (cs)) { sel = (s); off = r; }           \
      else r -= (cs);                                 \
    }
    MSTEP(c0, 0) MSTEP(c1, 1) MSTEP(c2, 2) MSTEP(c3, 3)
    MSTEP(c4, 4) MSTEP(c5, 5) MSTEP(c6, 6) MSTEP(c7, 7)
#undef MSTEP
    // First non-empty segment (rank-0 source) for the fill value.
    int f0 = (c0 > 0) ? 0 : (c1 > 0) ? 1 : (c2 > 0) ? 2 : (c3 > 0) ? 3
           : (c4 > 0) ? 4 : (c5 > 0) ? 5 : (c6 > 0) ? 6 : 7;
    int sseg = (sel >= 0) ? sel : f0;
    int soff = (sel >= 0) ? off : 0;
    sidx[t] = segidx[((size_t)g * SEG_ + sseg) * K_ + soff];
  }
  __syncthreads();
  for (int f = t; f < 32 * 24; f += 128) {   // 24 half4-groups per 96-col row
    int k = f / 24, q = f - k * 24;
    half4 hv;
    if (q < 17) {
      float4 v = *(const float4*)&ptsT[(size_t)(b * N_ + sidx[k]) * 68 + q * 4];
      if (q == 0) { v.x -= ctr0; v.y -= ctr1; v.z -= ctr2; }
      hv[0] = (_Float16)v.x; hv[1] = (_Float16)v.y;
      hv[2] = (_Float16)v.z; hv[3] = (_Float16)v.w;
    } else {
      hv[0] = (_Float16)0.f; hv[1] = (_Float16)0.f;
      hv[2] = (_Float16)0.f; hv[3] = (_Float16)0.f;
    }
    *(half4*)&sfeat16[k * 104 + q * 4] = hv;
  }
  __syncthreads();
  int w = t >> 6, l = t & 63;                // 2 waves: w in {0,1}
  int lg = l >> 4, lr = l & 15;
  f32x4 acc[2][2] = {};   // [mt = k-rows 0-15/16-31][ct = cout tile]
#pragma unroll
  for (int kk = 0; kk < 96; kk += 32) {
    half8 a0 = *(const half8*)&sfeat16[lr * 104 + kk + lg * 8];
    half8 a1 = *(const half8*)&sfeat16[(16 + lr) * 104 + kk + lg * 8];
    half8 bb0 = *(const half8*)&sw16[(w * 32 + lr) * 104 + kk + lg * 8];
    half8 bb1 = *(const half8*)&sw16[(w * 32 + 16 + lr) * 104 + kk + lg * 8];
    acc[0][0] = __builtin_amdgcn_mfma_f32_16x16x32_f16(a0, bb0, acc[0][0], 0, 0, 0);
    acc[0][1] = __builtin_amdgcn_mfma_f32_16x16x32_f16(a0, bb1, acc[0][1], 0, 0, 0);
    acc[1][0] = __builtin_amdgcn_mfma_f32_16x16x32_f16(a1, bb0, acc[1][0], 0, 0, 0);
    acc[1][1] = __builtin_amdgcn_mfma_f32_16x16x32_f16(a1, bb1, acc[1][1], 0, 0, 0);
  }
#pragma unroll
  for (int ct = 0; ct < 2; ++ct) {
    int c = w * 32 + ct * 16 + lr;           // this lane's channel
    float bias = b0[c];
#pragma unroll
    for (int mt = 0; mt < 2; ++mt) {
      float s1 = 0.f, s2 = 0.f;
#pragma unroll
      for (int r = 0; r < 4; ++r) {          // k = mt*16 + lg*4 + r
        float v = acc[mt][ct][r] + bias;
        sstage[(mt * 16 + lg * 4 + r) * 64 + c] = (_Float16)v;
        s1 += v; s2 += v * v;
      }
      red0[c * 8 + mt * 4 + lg] = s1;
      red1[c * 8 + mt * 4 + lg] = s2;
    }
  }
  __syncthreads();
  if (t < 64) {
    float s1 = 0.f, s2 = 0.f;
#pragma unroll
    for (int qn = 0; qn < 8; ++qn) { s1 += red0[t * 8 + qn]; s2 += red1[t * 8 + qn]; }
    part[(size_t)g * 256 + t] = s1;
    part[(size_t)g * 256 + 64 + t] = s2;
  }
  uint4* dst = (uint4*)(pre + (size_t)g * 2048);
  const uint4* srcv = (const uint4*)sstage;
  dst[t] = srcv[t];
  dst[t + 128] = srcv[t + 128];
}

// ---------------------------------------------------------------------------
// Stats reduce (coalesced, R8-proven): thread t owns channel t; block sums 64
// consecutive rows; one atomicAdd per (block, channel). accum pre-zeroed.
// R22 lesson: this two-level scheme (64-row in-register sum, then ONE atomic
// per block-channel) is required — direct per-conv-block atomics serialize.
// ---------------------------------------------------------------------------
__global__ __launch_bounds__(256) void red_kernel(
    const float* __restrict__ part, float* __restrict__ accum) {
  int t = threadIdx.x;
  size_t base = (size_t)blockIdx.x * 64 * 256 + t;
  float a = 0.f;
#pragma unroll 8
  for (int r = 0; r < 64; ++r) a += part[base + (size_t)r * 256];
  atomicAdd(accum + t, a);
}

// ---------------------------------------------------------------------------
// Layer 1 conv — R25-proven MFMA f16 path (c_out=64, 128 thr = 2 waves x 32
// channels). BN0+relu rounded to f16, w1 rounded to f16, f32 MFMA accumulate.
// Epilogue shape identical to pre-MFMA scheme; t<64 reduction + pre2 copy
// untouched.
// ---------------------------------------------------------------------------
__global__ __launch_bounds__(128) void convB_kernel(
    const _Float16* __restrict__ pre, const float* __restrict__ accum,
    const float* __restrict__ gam, const float* __restrict__ bet,
    const float* __restrict__ w1, const float* __restrict__ b1,
    _Float16* __restrict__ pre2, float* __restrict__ part) {
  __shared__ __align__(16) _Float16 sfeat16[32 * 72];   // [k][cin], pad 72
  __shared__ __align__(16) _Float16 sw16[64 * 72];      // [cout][cin], pad 72
  __shared__ float red0[64 * 8], red1[64 * 8];
  __shared__ __align__(16) _Float16 sstage[2048];
  __shared__ float ssc[64], ssh[64];
  int g = blockIdx.x;
  int t = threadIdx.x;
  if (t < 64) {
    float mu = accum[t] * (1.f / CNT_F);
    float var = accum[64 + t] * (1.f / CNT_F) - mu * mu;
    float sc = gam[t] / sqrtf(var + EPS_);
    ssc[t] = sc; ssh[t] = bet[t] - mu * sc;
  }
  for (int m = t; m < 1024; m += 128) {      // w1: 4096 f32 -> f16
    int c = m >> 4, ci = (m & 15) * 4;
    float4 wv = *(const float4*)&w1[m * 4];
    sw16[c * 72 + ci]     = (_Float16)wv.x;
    sw16[c * 72 + ci + 1] = (_Float16)wv.y;
    sw16[c * 72 + ci + 2] = (_Float16)wv.z;
    sw16[c * 72 + ci + 3] = (_Float16)wv.w;
  }
  __syncthreads();
  {
    const half8* src8 = (const half8*)(pre + (size_t)g * 2048);
    int r = t >> 2, c0 = (t & 3) * 16;       // thread owns row r, cols c0..c0+15
    half8 h0 = src8[t * 2], h1 = src8[t * 2 + 1];
    half8 o0, o1;
#pragma unroll
    for (int e = 0; e < 8; ++e) {
      float v = (float)h0[e] * ssc[c0 + e] + ssh[c0 + e];
      o0[e] = (_Float16)fmaxf(v, 0.f);
    }
#pragma unroll
    for (int e = 0; e < 8; ++e) {
      float v = (float)h1[e] * ssc[c0 + 8 + e] + ssh[c0 + 8 + e];
      o1[e] = (_Float16)fmaxf(v, 0.f);
    }
    *(half8*)&sfeat16[r * 72 + c0] = o0;
    *(half8*)&sfeat16[r * 72 + c0 + 8] = o1;
  }
  __syncthreads();
  int w = t >> 6, l = t & 63;                // 2 waves: w in {0,1}
  int lg = l >> 4, lr = l & 15;
  f32x4 acc[2][2] = {};   // [mt = k-rows 0-15/16-31][ct = cout tile]
#pragma unroll
  for (int kk = 0; kk < 64; kk += 32) {
    half8 a0 = *(const half8*)&sfeat16[lr * 72 + kk + lg * 8];
    half8 a1 = *(const half8*)&sfeat16[(16 + lr) * 72 + kk + lg * 8];
    half8 bb0 = *(const half8*)&sw16[(w * 32 + lr) * 72 + kk + lg * 8];
    half8 bb1 = *(const half8*)&sw16[(w * 32 + 16 + lr) * 72 + kk + lg * 8];
    acc[0][0] = __builtin_amdgcn_mfma_f32_16x16x32_f16(a0, bb0, acc[0][0], 0, 0, 0);
    acc[0][1] = __builtin_amdgcn_mfma_f32_16x16x32_f16(a0, bb1, acc[0][1], 0, 0, 0);
    acc[1][0] = __builtin_amdgcn_mfma_f32_16x16x32_f16(a1, bb0, acc[1][0], 0, 0, 0);
    acc[1][1] = __builtin_amdgcn_mfma_f32_16x16x32_f16(a1, bb1, acc[1][1], 0, 0, 0);
  }
#pragma unroll
  for (int ct = 0; ct < 2; ++ct) {
    int c = w * 32 + ct * 16 + lr;           // this lane's channel
    float bias = b1[c];
#pragma unroll
    for (int mt = 0; mt < 2; ++mt) {
      float s1 = 0.f, s2 = 0.f;
#pragma unroll
      for (int r = 0; r < 4; ++r) {          // k = mt*16 + lg*4 + r
        float v = acc[mt][ct][r] + bias;
        sstage[(mt * 16 + lg * 4 + r) * 64 + c] = (_Float16)v;
        s1 += v; s2 += v * v;
      }
      red0[c * 8 + mt * 4 + lg] = s1;
      red1[c * 8 + mt * 4 + lg] = s2;
    }
  }
  __syncthreads();
  if (t < 64) {
    float s1 = 0.f, s2 = 0.f;
#pragma unroll
    for (int qn = 0; qn < 8; ++qn) { s1 += red0[t * 8 + qn]; s2 += red1[t * 8 + qn]; }
    part[(size_t)g * 256 + t] = s1;
    part[(size_t)g * 256 + 64 + t] = s2;
  }
  uint4* dst = (uint4*)(pre2 + (size_t)g * 2048);
  const uint4* srcv = (const uint4*)sstage;
  dst[t] = srcv[t];
  dst[t + 128] = srcv[t + 128];
}

// ---------------------------------------------------------------------------
// Layer 2 conv — R24-proven MFMA f16 path. Fragment layouts verified;
// epilogue shape identical to pre-MFMA scheme; max-over-k argument
// (relu∘BN monotone) unchanged.
// ---------------------------------------------------------------------------
__global__ __launch_bounds__(256) void convC_kernel(
    const _Float16* __restrict__ pre2, const float* __restrict__ accum,
    const float* __restrict__ gam, const float* __restrict__ bet,
    const float* __restrict__ w2, const float* __restrict__ b2,
    float* __restrict__ mm, float* __restrict__ part) {
  __shared__ __align__(16) _Float16 sfeat16[32 * 72];   // [k][cin], pad 72
  __shared__ __align__(16) _Float16 sw16[128 * 72];     // [cout][cin], pad 72
  __shared__ float red0[128 * 8], red1[128 * 8];
  __shared__ float rmax[128 * 8], rmin[128 * 8];
  __shared__ float ssc[64], ssh[64];
  int g = blockIdx.x;
  int t = threadIdx.x;
  if (t < 64) {
    float mu = accum[t] * (1.f / CNT_F);
    float var = accum[64 + t] * (1.f / CNT_F) - mu * mu;
    float sc = gam[t] / sqrtf(var + EPS_);
    ssc[t] = sc; ssh[t] = bet[t] - mu * sc;
  }
  for (int m = t; m < 2048; m += 256) {      // w2: 8192 f32 -> f16
    int c = m >> 4, ci = (m & 15) * 4;
    float4 wv = *(const float4*)&w2[m * 4];
    sw16[c * 72 + ci]     = (_Float16)wv.x;
    sw16[c * 72 + ci + 1] = (_Float16)wv.y;
    sw16[c * 72 + ci + 2] = (_Float16)wv.z;
    sw16[c * 72 + ci + 3] = (_Float16)wv.w;
  }
  __syncthreads();
  {
    const half8* src8 = (const half8*)(pre2 + (size_t)g * 2048);
    int r = t >> 3, c0 = (t & 7) * 8;        // thread owns row r, cols c0..c0+7
    half8 h0 = src8[t];
    half8 o;
#pragma unroll
    for (int e = 0; e < 8; ++e) {
      float v = (float)h0[e] * ssc[c0 + e] + ssh[c0 + e];
      o[e] = (_Float16)fmaxf(v, 0.f);
    }
    *(half8*)&sfeat16[r * 72 + c0] = o;
  }
  __syncthreads();
  int w = t >> 6, l = t & 63;
  int lg = l >> 4, lr = l & 15;
  f32x4 acc[2][2] = {};   // [mt = k-rows 0-15/16-31][ct = cout tile]
#pragma unroll
  for (int kk = 0; kk < 64; kk += 32) {
    half8 a0 = *(const half8*)&sfeat16[lr * 72 + kk + lg * 8];
    half8 a1 = *(const half8*)&sfeat16[(16 + lr) * 72 + kk + lg * 8];
    half8 bb0 = *(const half8*)&sw16[(w * 32 + lr) * 72 + kk + lg * 8];
    half8 bb1 = *(const half8*)&sw16[(w * 32 + 16 + lr) * 72 + kk + lg * 8];
    acc[0][0] = __builtin_amdgcn_mfma_f32_16x16x32_f16(a0, bb0, acc[0][0], 0, 0, 0);
    acc[0][1] = __builtin_amdgcn_mfma_f32_16x16x32_f16(a0, bb1, acc[0][1], 0, 0, 0);
    acc[1][0] = __builtin_amdgcn_mfma_f32_16x16x32_f16(a1, bb0, acc[1][0], 0, 0, 0);
    acc[1][1] = __builtin_amdgcn_mfma_f32_16x16x32_f16(a1, bb1, acc[1][1], 0, 0, 0);
  }
#pragma unroll
  for (int ct = 0; ct < 2; ++ct) {
    int c = w * 32 + ct * 16 + lr;           // this lane's channel
    float bias = b2[c];
#pragma unroll
    for (int mt = 0; mt < 2; ++mt) {
      float s1 = 0.f, s2 = 0.f, mx = -3.4e38f, mn = 3.4e38f;
#pragma unroll
      for (int r = 0; r < 4; ++r) {          // k = mt*16 + lg*4 + r
        float v = acc[mt][ct][r] + bias;
        s1 += v; s2 += v * v;
        mx = fmaxf(mx, v); mn = fminf(mn, v);
      }
      red0[c * 8 + mt * 4 + lg] = s1;
      red1[c * 8 + mt * 4 + lg] = s2;
      rmax[c * 8 + mt * 4 + lg] = mx;
      rmin[c * 8 + mt * 4 + lg] = mn;
    }
  }
  __syncthreads();
  if (t < 128) {
    float s1 = 0.f, s2 = 0.f, mx = -3.4e38f, mn = 3.4e38f;
#pragma unroll
    for (int qn = 0; qn < 8; ++qn) {
      s1 += red0[t * 8 + qn]; s2 += red1[t * 8 + qn];
      mx = fmaxf(mx, rmax[t * 8 + qn]); mn = fminf(mn, rmin[t * 8 + qn]);
    }
    part[(size_t)g * 256 + t] = s1;
    part[(size_t)g * 256 + 128 + t] = s2;
    mm[(size_t)g * 256 + t] = mx;
    mm[(size_t)g * 256 + 128 + t] = mn;
  }
}

// ---------------------------------------------------------------------------
// Final (coalesced, R8-proven): block = (b, 64-s tile); read mm rows, LDS
// transpose, write out[B,128,S] coalesced in s.
// ---------------------------------------------------------------------------
__global__ __launch_bounds__(256) void fin_kernel(
    const float* __restrict__ mm, const float* __restrict__ accum,
    const float* __restrict__ gam, const float* __restrict__ bet,
    float* __restrict__ out1) {
  __shared__ float tile[128 * 65];
  __shared__ float ssc[128], ssh[128];
  int blk = blockIdx.x;
  int b = blk >> 4;
  int s0 = (blk & 15) << 6;
  int t = threadIdx.x;
  if (t < 128) {
    float mu = accum[t] * (1.f / CNT_F);
    float var = accum[128 + t] * (1.f / CNT_F) - mu * mu;
    float sc = gam[t] / sqrtf(var + EPS_);
    ssc[t] = sc; ssh[t] = bet[t] - mu * sc;
  }
  __syncthreads();
  for (int f = t; f < 64 * 128; f += 256) {
    int sl = f >> 7, c = f & 127;
    const float* row = mm + (size_t)(b * S_ + s0 + sl) * 256;
    float sc = ssc[c];
    float v = (sc >= 0.f) ? row[c] : row[128 + c];
    tile[c * 65 + sl] = fmaxf(v * sc + ssh[c], 0.f);
  }
  __syncthreads();
  for (int f = t; f < 128 * 64; f += 256) {
    int c = f >> 6, sl = f & 63;
    out1[(size_t)b * 131072 + c * 1024 + s0 + sl] = tile[c * 65 + sl];
  }
}

// ---------------------------------------------------------------------------
extern "C" void kernel_launch(void* const* d_in, const int* in_sizes, int n_in,
                              void* d_out, int out_size, void* d_ws, size_t ws_size,
                              hipStream_t stream) {
  const float* xyz = (const float*)d_in[0];
  const float* pts = (const float*)d_in[1];
  const float* w0  = (const float*)d_in[2];
  const float* b0  = (const float*)d_in[3];
  const float* g0  = (const float*)d_in[4];
  const float* bt0 = (const float*)d_in[5];
  const float* w1  = (const float*)d_in[6];
  const float* b1  = (const float*)d_in[7];
  const float* g1  = (const float*)d_in[8];
  const float* bt1 = (const float*)d_in[9];
  const float* w2  = (const float*)d_in[10];
  const float* b2  = (const float*)d_in[11];
  const float* g2  = (const float*)d_in[12];
  const float* bt2 = (const float*)d_in[13];
  float* out = (float*)d_out;

  char* ws = (char*)d_ws;
  float*    nxyz  = (float*)(ws + OFF_NXYZ);
  float*    ptsT  = (float*)(ws + OFF_PTST);
  _Float16* pre   = (_Float16*)(ws + OFF_PRE);
  _Float16* pre2  = (_Float16*)(ws + OFF_PRE2);
  float*    part  = (float*)(ws + OFF_PART);
  float*    mm    = (float*)(ws + OFF_MM3);
  float*    accum = (float*)(ws + OFF_ACC);
  // R19-proven: bq scratch aliases PRE2 (first written by convB, strictly
  // after convA — the last segidx reader). Never PRE (R18 crash).
  int*      segidx = (int*)(ws + OFF_PRE2);
  int*      segcnt = (int*)(ws + OFF_PRE2 + 16777216u);

  (void)hipMemsetAsync(accum, 0, 3 * 256 * sizeof(float), stream);

  // Fused: blocks 0..15 = FPS (16 CUs busy), blocks 16..1039 = transpose
  // riding on the otherwise-idle 240 CUs.
  fps_tr_kernel<<<B_ + B_ * (N_ / 64), 256, 0, stream>>>(xyz, pts, nxyz, out,
                                                         ptsT);
  bq_seg_kernel<<<dim3((B_ * S_) / 64, SEG_), 64, 0, stream>>>(xyz, nxyz,
                                                               segidx, segcnt);

  convA_kernel<<<B_ * S_, 128, 0, stream>>>(ptsT, nxyz, segidx, segcnt, w0, b0,
                                            pre, part);
  red_kernel<<<256, 256, 0, stream>>>(part, accum);
  convB_kernel<<<B_ * S_, 128, 0, stream>>>(pre, accum, g0, bt0, w1, b1, pre2, part);
  red_kernel<<<256, 256, 0, stream>>>(part, accum + 256);
  convC_kernel<<<B_ * S_, 256, 0, stream>>>(pre2, accum + 256, g1, bt1, w2, b2, mm, part);
  red_kernel<<<256, 256, 0, stream>>>(part, accum + 512);
  fin_kernel<<<B_ * (S_ / 64), 256, 0, stream>>>(mm, accum + 512, g2, bt2,
                                                 out + B_ * 3 * S_);
}

// Round 16
// 1106.093 us; speedup vs baseline: 1.8540x; 1.0232x over previous
//
#include <hip/hip_runtime.h>
#include <cstdint>
#include <cstddef>

// Problem constants
#define B_    16
#define N_    4096
#define S_    1024     // NPOINT
#define K_    32       // NSAMPLE
#define CNT_F 524288.0f   // B*S*K
#define EPS_  1e-5f

// Ball-query segmentation (R14-proven): 8 index-range segments per query.
#define SEG_    8
#define SEGLEN_ (N_ / SEG_)   // 512

// Conv groups-per-block batching (R27): weights/BN staged once per block.
#define GPB_    4

// Workspace layout (bytes). Total ~188 MB.
#define OFF_NXYZ 0u                    // [B][S][3] f32              196,608
#define OFF_PTST 2293760u              // [B][N][68] f32 (xyz|pts|0) 17,825,792
#define OFF_PRE  20119552u             // [BS][32][64] f16          67,108,864
#define OFF_PRE2 87228416u             // [BS][32][64] f16          67,108,864
#define OFF_PART 154337280u            // [BS][256] f32             16,777,216
#define OFF_MM3  171114496u            // [BS][2][128] f32          16,777,216
#define OFF_ACC  187891712u            // [3][256] f32                   3,072
// R19-proven: bq segment scratch lives in the PRE2 region (convB is its
// first writer, strictly after convA — the last segidx reader). Never PRE
// (convA writes pre while reading segidx -> race, R18 crash).
// R22 LESSON: do NOT replace part+red_kernel with per-block atomics — 16384
// blocks x 128-256 atomicAdds to the same words serialize at L2 (+750 us).
//   segidx [BS][SEG][K] i32 = 16,777,216 ; segcnt [BS][SEG] i32 = 524,288

typedef _Float16 half8 __attribute__((ext_vector_type(8)));
typedef _Float16 half4 __attribute__((ext_vector_type(4)));
typedef float f32x4 __attribute__((ext_vector_type(4)));

// ---------------------------------------------------------------------------
// u64-key DPP max step (R17-proven). Keys are positive-f64 bit patterns
// (sign 0, exponent <= 0x3FB: never NaN/Inf/zero), so v_max_f64 ==
// lexicographic u64 max == the R8-proven comparator (max value, tie -> min
// index). Same rotation network as the proven dpp_argmax_step.
// ---------------------------------------------------------------------------
template <int CTRL, int RM>
__device__ __forceinline__ uint64_t dpp_max64(uint64_t k) {
  int lo = __builtin_amdgcn_update_dpp((int)(uint32_t)k, (int)(uint32_t)k,
                                       CTRL, RM, 0xf, false);
  int hi = __builtin_amdgcn_update_dpp((int)(uint32_t)(k >> 32),
                                       (int)(uint32_t)(k >> 32),
                                       CTRL, RM, 0xf, false);
  uint64_t o = ((uint64_t)(uint32_t)hi << 32) | (uint32_t)lo;
  double m = fmax(__longlong_as_double((long long)k),
                  __longlong_as_double((long long)o));
  return (uint64_t)__double_as_longlong(m);
}

// ---------------------------------------------------------------------------
// FPS — R17/R20-proven form (653-662 us measured, VGPR 88): u64-key
// tree/DPP, merge keys -> decode far -> sx/sy/sz[far] broadcast reads.
// 256 thr / 4 waves is this structure's optimum (R13/R21 bracketing).
// Fused transpose on blocks >= 16 (R5-proven). Selection exact (R1-R17).
// ---------------------------------------------------------------------------
__global__ __launch_bounds__(256) void fps_tr_kernel(
    const float* __restrict__ xyz, const float* __restrict__ pts,
    float* __restrict__ nxyz, float* __restrict__ out0,
    float* __restrict__ ptsT) {
#pragma clang fp contract(off)
  __shared__ __align__(16) char smem[61504];
  int t = threadIdx.x;

  if (blockIdx.x >= B_) {
    // ---------------- transpose role (R0-proven pattern) ----------------
    float* tile = (float*)smem;            // 64*69 floats = 17,664 B
    int blk = blockIdx.x - B_;
    int b = blk >> 6;
    int n0 = (blk & 63) << 6;
    int wave = t >> 6, ln = t & 63;
    int n = n0 + ln;
    for (int cc = wave; cc < 68; cc += 4) {
      float v;
      if (cc < 3)       v = xyz[(size_t)(b * 3 + cc) * N_ + n];
      else if (cc < 67) v = pts[(size_t)(b * 64 + (cc - 3)) * N_ + n];
      else              v = 0.f;
      tile[ln * 69 + cc] = v;
    }
    __syncthreads();
    for (int f = t; f < 64 * 68; f += 256) {
      int r = f / 68, c = f - r * 68;
      ptsT[(size_t)(b * N_ + n0 + r) * 68 + c] = tile[r * 69 + c];
    }
    return;
  }

  // ------------------------- FPS role (R17 verbatim) -------------------------
  float*    sx    = (float*)smem;        // [4096]
  float*    sy    = sx + N_;
  float*    sz    = sy + N_;
  float*    scent = sz + N_;             // [3072]
  uint64_t* skey  = (uint64_t*)(scent + 3 * S_);  // [2][4] (off 61440, 16B ok)

  int b = blockIdx.x;
  const float* xb = xyz + (size_t)b * 3 * N_;
  float xr[16], yr[16], zr[16], dist[16];
  uint32_t Larr[16];
#pragma unroll
  for (int j = 0; j < 16; ++j) {
    int i = j * 256 + t;                      // coalesced: lanes contiguous
    float x = xb[i], y = xb[N_ + i], z = xb[2 * N_ + i];
    xr[j] = x; yr[j] = y; zr[j] = z;
    sx[i] = x; sy[i] = y; sz[i] = z;          // bank = t%32: conflict-free
    dist[j] = 1e10f;
    // j*256 and t occupy disjoint bits -> XOR == 0x7FFFFFFF ^ (j*256+t).
    Larr[j] = 0x7FFFFFFFu ^ (uint32_t)(j * 256 + t);
  }
  __syncthreads();

  int far = 0, par = 0;
  for (int s = 0; s < S_; ++s) {
    float cx = sx[far], cy = sy[far], cz = sz[far];   // uniform broadcast read
    if (t == 0) {
      scent[s * 3]     = cx;
      scent[s * 3 + 1] = cy;
      scent[s * 3 + 2] = cz;
    }
    // Distance update (arithmetic unchanged) + key build.
    uint64_t ku[16];
#pragma unroll
    for (int j = 0; j < 16; ++j) {
      float dx = xr[j] - cx, dy = yr[j] - cy, dz = zr[j] - cz;
      float d = dx * dx + dy * dy + dz * dz;  // left-assoc, no fma
      float nd = fminf(dist[j], d);
      dist[j] = nd;
      ku[j] = ((uint64_t)__float_as_uint(nd) << 31) | Larr[j];
    }
    // Depth-4 max tree over unique keys == keep-left strict-> tree == serial
    // first-index-wins scan. Static indices -> registers.
#pragma unroll
    for (int st = 1; st < 16; st <<= 1) {
#pragma unroll
      for (int j0 = 0; j0 < 16; j0 += (st << 1)) {
        double a = __longlong_as_double((long long)ku[j0]);
        double c2 = __longlong_as_double((long long)ku[j0 + st]);
        ku[j0] = (uint64_t)__double_as_longlong(fmax(a, c2));
      }
    }
    uint64_t k = ku[0];
    // Wave max (VALU-only), winner key in lane 63 of each wave.
    k = dpp_max64<0x121, 0xf>(k);  // row_ror:1
    k = dpp_max64<0x122, 0xf>(k);  // row_ror:2
    k = dpp_max64<0x124, 0xf>(k);  // row_ror:4
    k = dpp_max64<0x128, 0xf>(k);  // row_ror:8
    k = dpp_max64<0x142, 0xa>(k);  // row_bcast15 -> rows 1,3
    k = dpp_max64<0x143, 0xc>(k);  // row_bcast31 -> rows 2,3
    if ((t & 63) == 63) skey[par * 4 + (t >> 6)] = k;
    __syncthreads();
    // Vectorized readback; u64 max over distinct keys (order-independent).
    ulonglong2 p0 = *(const ulonglong2*)&skey[par * 4];
    ulonglong2 p1 = *(const ulonglong2*)&skey[par * 4 + 2];
    uint64_t m = p0.x;
    if (p0.y > m) m = p0.y;
    if (p1.x > m) m = p1.x;
    if (p1.y > m) m = p1.y;
    far = (int)((~(uint32_t)m) & 0xFFFu);   // low 31 bits = 0x7FFFFFFF ^ idx
    par ^= 1;  // double-buffered slots -> one barrier per iteration
  }
  __syncthreads();
  // Coalesced output writes from LDS staging.
  for (int f = t; f < 3 * S_; f += 256)
    nxyz[(size_t)b * 3 * S_ + f] = scent[f];        // [B][S][3]
  for (int s = t; s < S_; s += 256) {               // [B][3][S]
    out0[(size_t)b * 3 * S_ + s]          = scent[s * 3];
    out0[(size_t)b * 3 * S_ + S_ + s]     = scent[s * 3 + 1];
    out0[(size_t)b * 3 * S_ + 2 * S_ + s] = scent[s * 3 + 2];
  }
}

// ---------------------------------------------------------------------------
// Ball query (R14-proven semantics, R19-proven float4 form): 8-way segmented
// scan; per-point fma chain, scan order, and early-exit checks IDENTICAL.
// ---------------------------------------------------------------------------
__global__ __launch_bounds__(64) void bq_seg_kernel(
    const float* __restrict__ xyz, const float* __restrict__ nxyz,
    int* __restrict__ segidx, int* __restrict__ segcnt) {
#pragma clang fp contract(off)
  int q = blockIdx.x * 64 + threadIdx.x;
  int seg = blockIdx.y;
  int b = q >> 10;
  const float* xb = xyz + (size_t)b * 3 * N_;
  float cx = nxyz[(size_t)q * 3];
  float cy = nxyz[(size_t)q * 3 + 1];
  float cz = nxyz[(size_t)q * 3 + 2];
  float A = fmaf(cz, cz, fmaf(cy, cy, cx * cx));
  int* out = segidx + ((size_t)q * SEG_ + seg) * K_;
  int found = 0;
  int i0 = seg * SEGLEN_;
#define BQ_POINT(xx, yy, zz, ii)                                   \
  {                                                                \
    float x = (xx), y = (yy), z = (zz);                            \
    float Bv  = fmaf(z, z, fmaf(y, y, x * x));                     \
    float dot = fmaf(cz, z, fmaf(cy, y, cx * x));                  \
    float d = fmaf(-2.0f, dot, A + Bv);                            \
    if (d <= 0.04f) {                                              \
      out[found] = (ii);                                           \
      ++found;                                                     \
      if (found >= K_) goto done;                                  \
    }                                                              \
  }
  for (int i = i0; i < i0 + SEGLEN_; i += 4) {
    float4 xv = *(const float4*)&xb[i];
    float4 yv = *(const float4*)&xb[N_ + i];
    float4 zv = *(const float4*)&xb[2 * N_ + i];
    BQ_POINT(xv.x, yv.x, zv.x, i)
    BQ_POINT(xv.y, yv.y, zv.y, i + 1)
    BQ_POINT(xv.z, yv.z, zv.z, i + 2)
    BQ_POINT(xv.w, yv.w, zv.w, i + 3)
  }
done:
  segcnt[q * SEG_ + seg] = found;
#undef BQ_POINT
}

// ---------------------------------------------------------------------------
// Layer 0 conv — R26-proven MFMA f16 path (K padded 68->96, zero pad cols),
// bq MERGE FUSED (R19-proven). Unchanged in R27 (gather/merge dominates; GPB
// batching left to the simpler convB/convC).
// ---------------------------------------------------------------------------
__global__ __launch_bounds__(128) void convA_kernel(
    const float* __restrict__ ptsT, const float* __restrict__ nxyz,
    const int* __restrict__ segidx, const int* __restrict__ segcnt,
    const float* __restrict__ w0, const float* __restrict__ b0,
    _Float16* __restrict__ pre, float* __restrict__ part) {
  __shared__ __align__(16) _Float16 sfeat16[32 * 104];  // [k][cin 0..95] pad 104
  __shared__ __align__(16) _Float16 sw16[64 * 104];     // [cout][cin] pad 104
  __shared__ float red0[64 * 8], red1[64 * 8];
  __shared__ __align__(16) _Float16 sstage[2048];
  __shared__ int sidx[32];
  __shared__ int scnt[8];
  int g = blockIdx.x;
  int t = threadIdx.x;
  int b = g >> 10;
  if (t < 8) scnt[t] = segcnt[(size_t)g * SEG_ + t];
  for (int f = t; f < 64 * 96; f += 128) {   // w0 -> f16, cols 67..95 zero
    int c = f / 96, ci = f - c * 96;
    sw16[c * 104 + ci] = (ci < 67) ? (_Float16)w0[c * 67 + ci] : (_Float16)0.f;
  }
  const float* nx = nxyz + (size_t)g * 3;
  float ctr0 = nx[0], ctr1 = nx[1], ctr2 = nx[2];
  __syncthreads();
  if (t < 32) {
    int c0 = scnt[0], c1 = scnt[1], c2 = scnt[2], c3 = scnt[3];
    int c4 = scnt[4], c5 = scnt[5], c6 = scnt[6], c7 = scnt[7];
    int r = t, sel = -1, off = 0;
#define MSTEP(cs, s)                                  \
    if (sel < 0) {                                    \
      if (r < (cs)) { sel = (s); off = r; }           \
      else r -= (cs);                                 \
    }
    MSTEP(c0, 0) MSTEP(c1, 1) MSTEP(c2, 2) MSTEP(c3, 3)
    MSTEP(c4, 4) MSTEP(c5, 5) MSTEP(c6, 6) MSTEP(c7, 7)
#undef MSTEP
    // First non-empty segment (rank-0 source) for the fill value.
    int f0 = (c0 > 0) ? 0 : (c1 > 0) ? 1 : (c2 > 0) ? 2 : (c3 > 0) ? 3
           : (c4 > 0) ? 4 : (c5 > 0) ? 5 : (c6 > 0) ? 6 : 7;
    int sseg = (sel >= 0) ? sel : f0;
    int soff = (sel >= 0) ? off : 0;
    sidx[t] = segidx[((size_t)g * SEG_ + sseg) * K_ + soff];
  }
  __syncthreads();
  for (int f = t; f < 32 * 24; f += 128) {   // 24 half4-groups per 96-col row
    int k = f / 24, q = f - k * 24;
    half4 hv;
    if (q < 17) {
      float4 v = *(const float4*)&ptsT[(size_t)(b * N_ + sidx[k]) * 68 + q * 4];
      if (q == 0) { v.x -= ctr0; v.y -= ctr1; v.z -= ctr2; }
      hv[0] = (_Float16)v.x; hv[1] = (_Float16)v.y;
      hv[2] = (_Float16)v.z; hv[3] = (_Float16)v.w;
    } else {
      hv[0] = (_Float16)0.f; hv[1] = (_Float16)0.f;
      hv[2] = (_Float16)0.f; hv[3] = (_Float16)0.f;
    }
    *(half4*)&sfeat16[k * 104 + q * 4] = hv;
  }
  __syncthreads();
  int w = t >> 6, l = t & 63;                // 2 waves: w in {0,1}
  int lg = l >> 4, lr = l & 15;
  f32x4 acc[2][2] = {};   // [mt = k-rows 0-15/16-31][ct = cout tile]
#pragma unroll
  for (int kk = 0; kk < 96; kk += 32) {
    half8 a0 = *(const half8*)&sfeat16[lr * 104 + kk + lg * 8];
    half8 a1 = *(const half8*)&sfeat16[(16 + lr) * 104 + kk + lg * 8];
    half8 bb0 = *(const half8*)&sw16[(w * 32 + lr) * 104 + kk + lg * 8];
    half8 bb1 = *(const half8*)&sw16[(w * 32 + 16 + lr) * 104 + kk + lg * 8];
    acc[0][0] = __builtin_amdgcn_mfma_f32_16x16x32_f16(a0, bb0, acc[0][0], 0, 0, 0);
    acc[0][1] = __builtin_amdgcn_mfma_f32_16x16x32_f16(a0, bb1, acc[0][1], 0, 0, 0);
    acc[1][0] = __builtin_amdgcn_mfma_f32_16x16x32_f16(a1, bb0, acc[1][0], 0, 0, 0);
    acc[1][1] = __builtin_amdgcn_mfma_f32_16x16x32_f16(a1, bb1, acc[1][1], 0, 0, 0);
  }
#pragma unroll
  for (int ct = 0; ct < 2; ++ct) {
    int c = w * 32 + ct * 16 + lr;           // this lane's channel
    float bias = b0[c];
#pragma unroll
    for (int mt = 0; mt < 2; ++mt) {
      float s1 = 0.f, s2 = 0.f;
#pragma unroll
      for (int r = 0; r < 4; ++r) {          // k = mt*16 + lg*4 + r
        float v = acc[mt][ct][r] + bias;
        sstage[(mt * 16 + lg * 4 + r) * 64 + c] = (_Float16)v;
        s1 += v; s2 += v * v;
      }
      red0[c * 8 + mt * 4 + lg] = s1;
      red1[c * 8 + mt * 4 + lg] = s2;
    }
  }
  __syncthreads();
  if (t < 64) {
    float s1 = 0.f, s2 = 0.f;
#pragma unroll
    for (int qn = 0; qn < 8; ++qn) { s1 += red0[t * 8 + qn]; s2 += red1[t * 8 + qn]; }
    part[(size_t)g * 256 + t] = s1;
    part[(size_t)g * 256 + 64 + t] = s2;
  }
  uint4* dst = (uint4*)(pre + (size_t)g * 2048);
  const uint4* srcv = (const uint4*)sstage;
  dst[t] = srcv[t];
  dst[t + 128] = srcv[t + 128];
}

// ---------------------------------------------------------------------------
// Stats reduce (coalesced, R8-proven): thread t owns channel t; block sums 64
// consecutive rows; one atomicAdd per (block, channel). accum pre-zeroed.
// R22 lesson: this two-level scheme (64-row in-register sum, then ONE atomic
// per block-channel) is required — direct per-conv-block atomics serialize.
// ---------------------------------------------------------------------------
__global__ __launch_bounds__(256) void red_kernel(
    const float* __restrict__ part, float* __restrict__ accum) {
  int t = threadIdx.x;
  size_t base = (size_t)blockIdx.x * 64 * 256 + t;
  float a = 0.f;
#pragma unroll 8
  for (int r = 0; r < 64; ++r) a += part[base + (size_t)r * 256];
  atomicAdd(accum + t, a);
}

// ---------------------------------------------------------------------------
// Layer 1 conv — R27: R25-proven MFMA f16 path with GPB_=4 group batching.
// Weights (sw16) and BN coeffs (ssc/ssh) staged ONCE per block; per-group
// values are BIT-IDENTICAL to the unbatched form (no operand changes).
// Barriers: [act ready] -> MFMA -> [red/sstage ready, sfeat16 reads done]
// -> part/copy -> [reuse safe]; each LDS buffer's read is separated from
// the next group's write by >= 1 barrier.
// ---------------------------------------------------------------------------
__global__ __launch_bounds__(128) void convB_kernel(
    const _Float16* __restrict__ pre, const float* __restrict__ accum,
    const float* __restrict__ gam, const float* __restrict__ bet,
    const float* __restrict__ w1, const float* __restrict__ b1,
    _Float16* __restrict__ pre2, float* __restrict__ part) {
  __shared__ __align__(16) _Float16 sfeat16[32 * 72];   // [k][cin], pad 72
  __shared__ __align__(16) _Float16 sw16[64 * 72];      // [cout][cin], pad 72
  __shared__ float red0[64 * 8], red1[64 * 8];
  __shared__ __align__(16) _Float16 sstage[2048];
  __shared__ float ssc[64], ssh[64];
  size_t g0 = (size_t)blockIdx.x * GPB_;
  int t = threadIdx.x;
  if (t < 64) {
    float mu = accum[t] * (1.f / CNT_F);
    float var = accum[64 + t] * (1.f / CNT_F) - mu * mu;
    float sc = gam[t] / sqrtf(var + EPS_);
    ssc[t] = sc; ssh[t] = bet[t] - mu * sc;
  }
  for (int m = t; m < 1024; m += 128) {      // w1: 4096 f32 -> f16 (once)
    int c = m >> 4, ci = (m & 15) * 4;
    float4 wv = *(const float4*)&w1[m * 4];
    sw16[c * 72 + ci]     = (_Float16)wv.x;
    sw16[c * 72 + ci + 1] = (_Float16)wv.y;
    sw16[c * 72 + ci + 2] = (_Float16)wv.z;
    sw16[c * 72 + ci + 3] = (_Float16)wv.w;
  }
  __syncthreads();

  int w = t >> 6, l = t & 63;                // 2 waves: w in {0,1}
  int lg = l >> 4, lr = l & 15;
  for (int gi = 0; gi < GPB_; ++gi) {
    size_t g = g0 + gi;
    {
      const half8* src8 = (const half8*)(pre + g * 2048);
      int r = t >> 2, c0 = (t & 3) * 16;     // thread owns row r, cols c0..c0+15
      half8 h0 = src8[t * 2], h1 = src8[t * 2 + 1];
      half8 o0, o1;
#pragma unroll
      for (int e = 0; e < 8; ++e) {
        float v = (float)h0[e] * ssc[c0 + e] + ssh[c0 + e];
        o0[e] = (_Float16)fmaxf(v, 0.f);
      }
#pragma unroll
      for (int e = 0; e < 8; ++e) {
        float v = (float)h1[e] * ssc[c0 + 8 + e] + ssh[c0 + 8 + e];
        o1[e] = (_Float16)fmaxf(v, 0.f);
      }
      *(half8*)&sfeat16[r * 72 + c0] = o0;
      *(half8*)&sfeat16[r * 72 + c0 + 8] = o1;
    }
    __syncthreads();   // act ready
    f32x4 acc[2][2] = {};   // re-zeroed per group
#pragma unroll
    for (int kk = 0; kk < 64; kk += 32) {
      half8 a0 = *(const half8*)&sfeat16[lr * 72 + kk + lg * 8];
      half8 a1 = *(const half8*)&sfeat16[(16 + lr) * 72 + kk + lg * 8];
      half8 bb0 = *(const half8*)&sw16[(w * 32 + lr) * 72 + kk + lg * 8];
      half8 bb1 = *(const half8*)&sw16[(w * 32 + 16 + lr) * 72 + kk + lg * 8];
      acc[0][0] = __builtin_amdgcn_mfma_f32_16x16x32_f16(a0, bb0, acc[0][0], 0, 0, 0);
      acc[0][1] = __builtin_amdgcn_mfma_f32_16x16x32_f16(a0, bb1, acc[0][1], 0, 0, 0);
      acc[1][0] = __builtin_amdgcn_mfma_f32_16x16x32_f16(a1, bb0, acc[1][0], 0, 0, 0);
      acc[1][1] = __builtin_amdgcn_mfma_f32_16x16x32_f16(a1, bb1, acc[1][1], 0, 0, 0);
    }
#pragma unroll
    for (int ct = 0; ct < 2; ++ct) {
      int c = w * 32 + ct * 16 + lr;         // this lane's channel
      float bias = b1[c];
#pragma unroll
      for (int mt = 0; mt < 2; ++mt) {
        float s1 = 0.f, s2 = 0.f;
#pragma unroll
        for (int r = 0; r < 4; ++r) {        // k = mt*16 + lg*4 + r
          float v = acc[mt][ct][r] + bias;
          sstage[(mt * 16 + lg * 4 + r) * 64 + c] = (_Float16)v;
          s1 += v; s2 += v * v;
        }
        red0[c * 8 + mt * 4 + lg] = s1;
        red1[c * 8 + mt * 4 + lg] = s2;
      }
    }
    __syncthreads();   // red/sstage ready; sfeat16 reads done
    if (t < 64) {
      float s1 = 0.f, s2 = 0.f;
#pragma unroll
      for (int qn = 0; qn < 8; ++qn) { s1 += red0[t * 8 + qn]; s2 += red1[t * 8 + qn]; }
      part[g * 256 + t] = s1;
      part[g * 256 + 64 + t] = s2;
    }
    uint4* dst = (uint4*)(pre2 + g * 2048);
    const uint4* srcv = (const uint4*)sstage;
    dst[t] = srcv[t];
    dst[t + 128] = srcv[t + 128];
    if (gi + 1 < GPB_) __syncthreads();  // sstage/red/sfeat16 reuse safe
  }
}

// ---------------------------------------------------------------------------
// Layer 2 conv — R27: R24-proven MFMA f16 path with GPB_=4 group batching
// (same barrier scheme as convB). Per-group values bit-identical.
// ---------------------------------------------------------------------------
__global__ __launch_bounds__(256) void convC_kernel(
    const _Float16* __restrict__ pre2, const float* __restrict__ accum,
    const float* __restrict__ gam, const float* __restrict__ bet,
    const float* __restrict__ w2, const float* __restrict__ b2,
    float* __restrict__ mm, float* __restrict__ part) {
  __shared__ __align__(16) _Float16 sfeat16[32 * 72];   // [k][cin], pad 72
  __shared__ __align__(16) _Float16 sw16[128 * 72];     // [cout][cin], pad 72
  __shared__ float red0[128 * 8], red1[128 * 8];
  __shared__ float rmax[128 * 8], rmin[128 * 8];
  __shared__ float ssc[64], ssh[64];
  size_t g0 = (size_t)blockIdx.x * GPB_;
  int t = threadIdx.x;
  if (t < 64) {
    float mu = accum[t] * (1.f / CNT_F);
    float var = accum[64 + t] * (1.f / CNT_F) - mu * mu;
    float sc = gam[t] / sqrtf(var + EPS_);
    ssc[t] = sc; ssh[t] = bet[t] - mu * sc;
  }
  for (int m = t; m < 2048; m += 256) {      // w2: 8192 f32 -> f16 (once)
    int c = m >> 4, ci = (m & 15) * 4;
    float4 wv = *(const float4*)&w2[m * 4];
    sw16[c * 72 + ci]     = (_Float16)wv.x;
    sw16[c * 72 + ci + 1] = (_Float16)wv.y;
    sw16[c * 72 + ci + 2] = (_Float16)wv.z;
    sw16[c * 72 + ci + 3] = (_Float16)wv.w;
  }
  __syncthreads();

  int w = t >> 6, l = t & 63;
  int lg = l >> 4, lr = l & 15;
  for (int gi = 0; gi < GPB_; ++gi) {
    size_t g = g0 + gi;
    {
      const half8* src8 = (const half8*)(pre2 + g * 2048);
      int r = t >> 3, c0 = (t & 7) * 8;      // thread owns row r, cols c0..c0+7
      half8 h0 = src8[t];
      half8 o;
#pragma unroll
      for (int e = 0; e < 8; ++e) {
        float v = (float)h0[e] * ssc[c0 + e] + ssh[c0 + e];
        o[e] = (_Float16)fmaxf(v, 0.f);
      }
      *(half8*)&sfeat16[r * 72 + c0] = o;
    }
    __syncthreads();   // act ready
    f32x4 acc[2][2] = {};   // re-zeroed per group
#pragma unroll
    for (int kk = 0; kk < 64; kk += 32) {
      half8 a0 = *(const half8*)&sfeat16[lr * 72 + kk + lg * 8];
      half8 a1 = *(const half8*)&sfeat16[(16 + lr) * 72 + kk + lg * 8];
      half8 bb0 = *(const half8*)&sw16[(w * 32 + lr) * 72 + kk + lg * 8];
      half8 bb1 = *(const half8*)&sw16[(w * 32 + 16 + lr) * 72 + kk + lg * 8];
      acc[0][0] = __builtin_amdgcn_mfma_f32_16x16x32_f16(a0, bb0, acc[0][0], 0, 0, 0);
      acc[0][1] = __builtin_amdgcn_mfma_f32_16x16x32_f16(a0, bb1, acc[0][1], 0, 0, 0);
      acc[1][0] = __builtin_amdgcn_mfma_f32_16x16x32_f16(a1, bb0, acc[1][0], 0, 0, 0);
      acc[1][1] = __builtin_amdgcn_mfma_f32_16x16x32_f16(a1, bb1, acc[1][1], 0, 0, 0);
    }
#pragma unroll
    for (int ct = 0; ct < 2; ++ct) {
      int c = w * 32 + ct * 16 + lr;         // this lane's channel
      float bias = b2[c];
#pragma unroll
      for (int mt = 0; mt < 2; ++mt) {
        float s1 = 0.f, s2 = 0.f, mx = -3.4e38f, mn = 3.4e38f;
#pragma unroll
        for (int r = 0; r < 4; ++r) {        // k = mt*16 + lg*4 + r
          float v = acc[mt][ct][r] + bias;
          s1 += v; s2 += v * v;
          mx = fmaxf(mx, v); mn = fminf(mn, v);
        }
        red0[c * 8 + mt * 4 + lg] = s1;
        red1[c * 8 + mt * 4 + lg] = s2;
        rmax[c * 8 + mt * 4 + lg] = mx;
        rmin[c * 8 + mt * 4 + lg] = mn;
      }
    }
    __syncthreads();   // red ready; sfeat16 reads done
    if (t < 128) {
      float s1 = 0.f, s2 = 0.f, mx = -3.4e38f, mn = 3.4e38f;
#pragma unroll
      for (int qn = 0; qn < 8; ++qn) {
        s1 += red0[t * 8 + qn]; s2 += red1[t * 8 + qn];
        mx = fmaxf(mx, rmax[t * 8 + qn]); mn = fminf(mn, rmin[t * 8 + qn]);
      }
      part[g * 256 + t] = s1;
      part[g * 256 + 128 + t] = s2;
      mm[g * 256 + t] = mx;
      mm[g * 256 + 128 + t] = mn;
    }
    if (gi + 1 < GPB_) __syncthreads();  // red/rmax/rmin/sfeat16 reuse safe
  }
}

// ---------------------------------------------------------------------------
// Final (coalesced, R8-proven): block = (b, 64-s tile); read mm rows, LDS
// transpose, write out[B,128,S] coalesced in s.
// ---------------------------------------------------------------------------
__global__ __launch_bounds__(256) void fin_kernel(
    const float* __restrict__ mm, const float* __restrict__ accum,
    const float* __restrict__ gam, const float* __restrict__ bet,
    float* __restrict__ out1) {
  __shared__ float tile[128 * 65];
  __shared__ float ssc[128], ssh[128];
  int blk = blockIdx.x;
  int b = blk >> 4;
  int s0 = (blk & 15) << 6;
  int t = threadIdx.x;
  if (t < 128) {
    float mu = accum[t] * (1.f / CNT_F);
    float var = accum[128 + t] * (1.f / CNT_F) - mu * mu;
    float sc = gam[t] / sqrtf(var + EPS_);
    ssc[t] = sc; ssh[t] = bet[t] - mu * sc;
  }
  __syncthreads();
  for (int f = t; f < 64 * 128; f += 256) {
    int sl = f >> 7, c = f & 127;
    const float* row = mm + (size_t)(b * S_ + s0 + sl) * 256;
    float sc = ssc[c];
    float v = (sc >= 0.f) ? row[c] : row[128 + c];
    tile[c * 65 + sl] = fmaxf(v * sc + ssh[c], 0.f);
  }
  __syncthreads();
  for (int f = t; f < 128 * 64; f += 256) {
    int c = f >> 6, sl = f & 63;
    out1[(size_t)b * 131072 + c * 1024 + s0 + sl] = tile[c * 65 + sl];
  }
}

// ---------------------------------------------------------------------------
extern "C" void kernel_launch(void* const* d_in, const int* in_sizes, int n_in,
                              void* d_out, int out_size, void* d_ws, size_t ws_size,
                              hipStream_t stream) {
  const float* xyz = (const float*)d_in[0];
  const float* pts = (const float*)d_in[1];
  const float* w0  = (const float*)d_in[2];
  const float* b0  = (const float*)d_in[3];
  const float* g0  = (const float*)d_in[4];
  const float* bt0 = (const float*)d_in[5];
  const float* w1  = (const float*)d_in[6];
  const float* b1  = (const float*)d_in[7];
  const float* g1  = (const float*)d_in[8];
  const float* bt1 = (const float*)d_in[9];
  const float* w2  = (const float*)d_in[10];
  const float* b2  = (const float*)d_in[11];
  const float* g2  = (const float*)d_in[12];
  const float* bt2 = (const float*)d_in[13];
  float* out = (float*)d_out;

  char* ws = (char*)d_ws;
  float*    nxyz  = (float*)(ws + OFF_NXYZ);
  float*    ptsT  = (float*)(ws + OFF_PTST);
  _Float16* pre   = (_Float16*)(ws + OFF_PRE);
  _Float16* pre2  = (_Float16*)(ws + OFF_PRE2);
  float*    part  = (float*)(ws + OFF_PART);
  float*    mm    = (float*)(ws + OFF_MM3);
  float*    accum = (float*)(ws + OFF_ACC);
  // R19-proven: bq scratch aliases PRE2 (first written by convB, strictly
  // after convA — the last segidx reader). Never PRE (R18 crash).
  int*      segidx = (int*)(ws + OFF_PRE2);
  int*      segcnt = (int*)(ws + OFF_PRE2 + 16777216u);

  (void)hipMemsetAsync(accum, 0, 3 * 256 * sizeof(float), stream);

  // Fused: blocks 0..15 = FPS (16 CUs busy), blocks 16..1039 = transpose
  // riding on the otherwise-idle 240 CUs.
  fps_tr_kernel<<<B_ + B_ * (N_ / 64), 256, 0, stream>>>(xyz, pts, nxyz, out,
                                                         ptsT);
  bq_seg_kernel<<<dim3((B_ * S_) / 64, SEG_), 64, 0, stream>>>(xyz, nxyz,
                                                               segidx, segcnt);

  convA_kernel<<<B_ * S_, 128, 0, stream>>>(ptsT, nxyz, segidx, segcnt, w0, b0,
                                            pre, part);
  red_kernel<<<256, 256, 0, stream>>>(part, accum);
  convB_kernel<<<(B_ * S_) / GPB_, 128, 0, stream>>>(pre, accum, g0, bt0, w1,
                                                     b1, pre2, part);
  red_kernel<<<256, 256, 0, stream>>>(part, accum + 256);
  convC_kernel<<<(B_ * S_) / GPB_, 256, 0, stream>>>(pre2, accum + 256, g1,
                                                     bt1, w2, b2, mm, part);
  red_kernel<<<256, 256, 0, stream>>>(part, accum + 512);
  fin_kernel<<<B_ * (S_ / 64), 256, 0, stream>>>(mm, accum + 512, g2, bt2,
                                                 out + B_ * 3 * S_);
}